// Round 10
// baseline (113.666 us; speedup 1.0000x reference)
//
#include <hip/hip_runtime.h>
#include <hip/hip_bf16.h>
#include <math.h>

typedef float4 f4;
typedef __attribute__((ext_vector_type(8))) short bf16x8;
typedef __attribute__((ext_vector_type(4))) float f32x4;
typedef __attribute__((ext_vector_type(16))) float f32x16;
typedef __attribute__((ext_vector_type(2))) unsigned u32x2;

#define CD   768
#define SEQ  1024
#define NHD  12
#define DH   64

__device__ __forceinline__ ushort f2bf(float x) {
    union { __hip_bfloat16 h; ushort u; } v;
    v.h = __float2bfloat16(x);
    return v.u;
}
__device__ __forceinline__ unsigned pk2bf(float a, float b) {
    union { __hip_bfloat162 h; unsigned u; } v;
    v.h = __float22bfloat162_rn(make_float2(a, b));
    return v.u;
}
__device__ __forceinline__ float bf2f(short u) {
    union { unsigned u; float f; } v;
    v.u = ((unsigned)(ushort)u) << 16;
    return v.f;
}
__device__ __forceinline__ void gload_lds16(const ushort* g, ushort* l) {
    __builtin_amdgcn_global_load_lds((const __attribute__((address_space(1))) void*)g,
                                     (__attribute__((address_space(3))) void*)l, 16, 0, 0);
}
__device__ __forceinline__ bf16x8 mk_bf16x8(unsigned a, unsigned b, unsigned c, unsigned d) {
    union { unsigned u[4]; bf16x8 v; } r;
    r.u[0] = a; r.u[1] = b; r.u[2] = c; r.u[3] = d;
    return r.v;
}

// ---------------- fp32 -> bf16 conversion pre-pass ---------------------------
// x, Wq, Wk, Wv -> row-major bf16; pw -> panel layout [k/64][n][k%64]
__global__ __launch_bounds__(256) void cvt_bf16_k(
    const float* __restrict__ x, const float* __restrict__ Wq,
    const float* __restrict__ Wk, const float* __restrict__ Wv,
    const float* __restrict__ pw, ushort* __restrict__ dst)
{
    const int idx = blockIdx.x * 256 + threadIdx.x;
    if (idx >= 1376256) return;
    const int e = idx << 2;
    if (e < 4915200) {
        const float* src; int off;
        if      (e < 3145728) { src = x;  off = e; }
        else if (e < 3735552) { src = Wq; off = e - 3145728; }
        else if (e < 4325376) { src = Wk; off = e - 3735552; }
        else                  { src = Wv; off = e - 4325376; }
        const f4 v = *(const f4*)(src + off);
        uint2 o;
        o.x = pk2bf(v.x, v.y);
        o.y = pk2bf(v.z, v.w);
        *(uint2*)(dst + e) = o;
    } else {
        const int off = e - 4915200;          // pw linear = n*768 + k
        const int n = off / CD, k = off - n * CD;
        const f4 v = *(const f4*)(pw + off);
        uint2 o;
        o.x = pk2bf(v.x, v.y);
        o.y = pk2bf(v.z, v.w);
        *(uint2*)(dst + 4915200 + ((size_t)(k >> 6) * CD + n) * 64 + (k & 63)) = o;
    }
}

// ---------------- QKV projection: bf16 MFMA GEMM, 2-phase dbuf ----------------
__global__ __launch_bounds__(256, 2) void qkv_mfma(
    const ushort* __restrict__ xbf,
    const ushort* __restrict__ wq, const ushort* __restrict__ wk, const ushort* __restrict__ wv,
    const float* __restrict__ bq, const float* __restrict__ bk, const float* __restrict__ bv,
    ushort* __restrict__ qbf, ushort* __restrict__ kbf, ushort* __restrict__ vbfT)
{
    __shared__ __align__(16) ushort Sq[32768];   // buf b: A at b*16384, B at +8192

    const int t = threadIdx.x;
    const int w = t >> 6, l = t & 63;
    const int lr = l & 15, lg = l >> 4;
    const int n0 = blockIdx.x << 7;
    const int m0 = blockIdx.y << 7;
    const int sel  = n0 / CD;
    const int nloc = n0 % CD;
    const ushort* Wb  = (sel == 0) ? wq : ((sel == 1) ? wk : wv);
    const float* bias = (sel == 0) ? bq : ((sel == 1) ? bk : bv);

    const int srow = (w << 3) + (l >> 3);
    const int scol = (l & 7) << 3;
    const ushort* Agl = xbf + (size_t)(m0 + srow) * CD + scol;
    const ushort* Bgl = Wb + (size_t)(nloc + srow) * CD + scol;

    f32x4 acc[4][4];
    #pragma unroll
    for (int mi = 0; mi < 4; ++mi)
        #pragma unroll
        for (int ni = 0; ni < 4; ++ni) acc[mi][ni] = (f32x4){0.f, 0.f, 0.f, 0.f};

    const int mb = (w >> 1) << 6, nb = (w & 1) << 6;

    #pragma unroll
    for (int i = 0; i < 4; ++i) {
        gload_lds16(Agl + (size_t)(i << 5) * CD, &Sq[(i << 11) + (w << 9)]);
        gload_lds16(Bgl + (size_t)(i << 5) * CD, &Sq[8192 + (i << 11) + (w << 9)]);
    }
    __syncthreads();

    for (int kt = 0; kt < 12; ++kt) {
        const int cb = (kt & 1) << 14;
        if (kt < 11) {
            const int nbuf = ((kt + 1) & 1) << 14;
            const int kc = (kt + 1) << 6;
            #pragma unroll
            for (int i = 0; i < 4; ++i) {
                gload_lds16(Agl + (size_t)(i << 5) * CD + kc, &Sq[nbuf + (i << 11) + (w << 9)]);
                gload_lds16(Bgl + (size_t)(i << 5) * CD + kc, &Sq[nbuf + 8192 + (i << 11) + (w << 9)]);
            }
        }
        #pragma unroll
        for (int kk = 0; kk < 2; ++kk) {
            bf16x8 af[4], bf[4];
            #pragma unroll
            for (int mi = 0; mi < 4; ++mi)
                af[mi] = *(const bf16x8*)&Sq[cb + (mb + (mi << 4) + lr) * 64 + (kk << 5) + (lg << 3)];
            #pragma unroll
            for (int ni = 0; ni < 4; ++ni)
                bf[ni] = *(const bf16x8*)&Sq[cb + 8192 + (nb + (ni << 4) + lr) * 64 + (kk << 5) + (lg << 3)];
            #pragma unroll
            for (int mi = 0; mi < 4; ++mi)
                #pragma unroll
                for (int ni = 0; ni < 4; ++ni)
                    acc[mi][ni] = __builtin_amdgcn_mfma_f32_16x16x32_bf16(af[mi], bf[ni], acc[mi][ni], 0, 0, 0);
        }
        __syncthreads();
    }

    ushort* Ep = Sq + (w << 12);

    float bl[4];
    #pragma unroll
    for (int ni = 0; ni < 4; ++ni) bl[ni] = bias[nloc + nb + (ni << 4) + lr];

    if (sel < 2) {
        #pragma unroll
        for (int mi = 0; mi < 4; ++mi)
            #pragma unroll
            for (int ni = 0; ni < 4; ++ni)
                #pragma unroll
                for (int reg = 0; reg < 4; ++reg)
                    Ep[((mi << 4) + (lg << 2) + reg) * 64 + (ni << 4) + lr] =
                        f2bf(acc[mi][ni][reg] + bl[ni]);
    } else {
        // V: plain transpose (R2-verified): Vt[d = ni*16+lr][s-col = mi*16+lg*4+reg]
        #pragma unroll
        for (int mi = 0; mi < 4; ++mi)
            #pragma unroll
            for (int ni = 0; ni < 4; ++ni)
                #pragma unroll
                for (int reg = 0; reg < 4; ++reg)
                    Ep[((ni << 4) + lr) * 64 + (mi << 4) + (lg << 2) + reg] =
                        f2bf(acc[mi][ni][reg] + bl[ni]);
    }

    const int bi   = m0 >> 10;
    const int si0  = (m0 & 1023) + mb;
    const int head = (nloc + nb) >> 6;
    const int bn   = bi * NHD + head;
    const ushort* src = Ep + l * 64;
    if (sel < 2) {
        ushort* dbf = (sel == 0) ? qbf : kbf;
        ushort* dst = dbf + (((size_t)bn << 10) + si0 + l) * 64;
        #pragma unroll
        for (int c = 0; c < 8; ++c)
            *(bf16x8*)(dst + (c << 3)) = *(const bf16x8*)(src + (c << 3));
    } else {
        ushort* dst = vbfT + (((size_t)(bn * DH + l)) << 10) + si0;
        #pragma unroll
        for (int c = 0; c < 8; ++c)
            *(bf16x8*)(dst + (c << 3)) = *(const bf16x8*)(src + (c << 3));
    }
}

// ---------------- decomposed rel-pos bias tables (reads bf16 q) --------------
// rel_h -> rhb3[bn][k2(32)][s(1024)]  (coalesced broadcast reads in attn)
// rel_w -> rwb2[bn][s][p(32)] permuted: p = 16*((k2>>2)&1) + (k2&3) + 4*(k2>>3)
__global__ __launch_bounds__(256) void rel_kernel(
    const ushort* __restrict__ qbf, const float* __restrict__ rph,
    const float* __restrict__ rpw,
    float* __restrict__ rhb3, float* __restrict__ rwb2)
{
    __shared__ float qsl[32][65];
    __shared__ float rhsl[32][65];
    __shared__ float rwsl[63][65];
    const int t  = threadIdx.x;
    const int h  = blockIdx.x;
    const int bn = blockIdx.y;
    const ushort* qp = qbf + (((size_t)bn << 10) + h * 32) * DH;

    {
        const int r = t >> 3, c8 = (t & 7) << 3;
        const bf16x8 v = *(const bf16x8*)(qp + (size_t)r * DH + c8);
        #pragma unroll
        for (int j = 0; j < 8; ++j) qsl[r][c8 + j] = bf2f(v[j]);
    }
    #pragma unroll
    for (int it = 0; it < 2; ++it) {
        int idx = (it << 8) + t;
        if (idx < 32 * 16) {
            int r = idx >> 4, c4 = (idx & 15) << 2;
            f4 w2 = *(const f4*)(rph + (size_t)(h + r) * DH + c4);
            rhsl[r][c4+0]=w2.x; rhsl[r][c4+1]=w2.y; rhsl[r][c4+2]=w2.z; rhsl[r][c4+3]=w2.w;
        }
    }
    #pragma unroll
    for (int it = 0; it < 4; ++it) {
        int idx = (it << 8) + t;
        if (idx < 63 * 16) {
            int r = idx >> 4, c4 = (idx & 15) << 2;
            f4 w2 = *(const f4*)(rpw + (size_t)r * DH + c4);
            rwsl[r][c4+0]=w2.x; rwsl[r][c4+1]=w2.y; rwsl[r][c4+2]=w2.z; rwsl[r][c4+3]=w2.w;
        }
    }
    __syncthreads();

    float oh[4], ow[4];
    const int row32 = t & 31;              // w coordinate
    const int K2    = (t >> 5) << 2;       // k2 base: 0,4,...,28
    #pragma unroll
    for (int i = 0; i < 4; ++i) {
        const int k2 = K2 + i;
        const float* qr = &qsl[row32][0];
        const float* th = &rhsl[31 - k2][0];
        const float* tw = &rwsl[row32 - k2 + 31][0];
        float sh = 0.f, sw = 0.f;
        #pragma unroll 8
        for (int dd = 0; dd < DH; ++dd) {
            sh = fmaf(qr[dd], th[dd], sh);
            sw = fmaf(qr[dd], tw[dd], sw);
        }
        oh[i] = sh; ow[i] = sw;
    }
    const int s = h * 32 + row32;
    // rel_h: 4 coalesced-per-group scalar stores
    #pragma unroll
    for (int i = 0; i < 4; ++i)
        rhb3[((size_t)((bn << 5) + K2 + i) << 10) + s] = oh[i];
    // rel_w: permuted reg-order, f4
    {
        const int p0 = (((t >> 5) & 1) << 4) + ((t >> 6) << 2);
        f4 vw; vw.x = ow[0]; vw.y = ow[1]; vw.z = ow[2]; vw.w = ow[3];
        *(f4*)(rwb2 + ((((size_t)bn << 10) + s) << 5) + p0) = vw;
    }
}

// ---------------- MFMA flash attention: 32x32 swapped-operand structure -------
// 64 q/block, 2 waves (each 32 q, all 64 keys). S^T = mfma(K, Q) -> lane owns
// one q-row; softmax in-registers; P->PV B-frags via cvt_pk + permlane32_swap
// (NO P LDS). PV: O^T = mfma(V^T, P^T). K,V dbuf via global_load_lds.
__global__ __launch_bounds__(128, 2) void attn_mfma(
    const ushort* __restrict__ qbf, const ushort* __restrict__ kbf,
    const ushort* __restrict__ vbfT,
    const float* __restrict__ rhb3, const float* __restrict__ rwb2,
    ushort* __restrict__ abf2)
{
    __shared__ __align__(16) ushort KV[2][8192];  // [buf][K:0..4095 | V:4096..]

    const int t  = threadIdx.x;
    const int w  = t >> 6, l = t & 63;
    const int g  = l >> 5, q5 = l & 31;
    const int qt = blockIdx.x, bn = blockIdx.y;
    const int q0 = qt << 6;
    const int srow = q0 + w * 32 + q5;

    // Q B-fragments: B[k=d][col=q]: lane col=q5, k = c*16 + g*8 + j
    const ushort* qp = qbf + (((size_t)bn << 10) + srow) * 64 + g * 8;
    bf16x8 qf[4];
    #pragma unroll
    for (int c = 0; c < 4; ++c) qf[c] = *(const bf16x8*)(qp + c * 16);

    // rel_w, reg-ordered (16 values for this lane's q)
    float rw16[16];
    {
        const float* rwp = rwb2 + ((((size_t)bn << 10) + srow) << 5) + (g << 4);
        #pragma unroll
        for (int i = 0; i < 4; ++i)
            *(f4*)&rw16[i * 4] = *(const f4*)(rwp + i * 4);
    }
    const float* rhp = rhb3 + (((size_t)bn << 5) << 10) + srow;

    // staging geometry
    const int rsub = l >> 3;
    const int coff = ((l & 7) ^ rsub) << 3;
    const size_t kbase = (size_t)bn << 16;
    const ushort* kp = kbf + kbase + (size_t)(w * 32 + rsub) * 64 + coff;
    const ushort* vp = vbfT + kbase + ((size_t)(w * 32 + rsub) << 10) + coff;
    const int ldsK = (w * 32) << 6;

    f32x16 oc[2];
    #pragma unroll
    for (int i = 0; i < 16; ++i) { oc[0][i] = 0.f; oc[1][i] = 0.f; }
    float lsum = 0.f;

    // prologue: tile 0 -> buf 0
    #pragma unroll
    for (int i = 0; i < 4; ++i) {
        gload_lds16(kp + (i << 9), &KV[0][ldsK + (i << 9)]);
        gload_lds16(vp + ((size_t)i << 13), &KV[0][4096 + ldsK + (i << 9)]);
    }
    __syncthreads();

    const int swz = q5 & 7;

    for (int kt = 0; kt < 16; ++kt) {
        const int cur = kt & 1;
        if (kt < 15) {
            ushort* nb = &KV[cur ^ 1][0];
            #pragma unroll
            for (int i = 0; i < 4; ++i) {
                gload_lds16(kp + ((size_t)(kt + 1) << 12) + (i << 9), nb + ldsK + (i << 9));
                gload_lds16(vp + ((size_t)i << 13) + ((kt + 1) << 6), nb + 4096 + ldsK + (i << 9));
            }
        }
        const ushort* Kl = &KV[cur][0];
        const ushort* Vt = &KV[cur][4096];
        const float rh0 = rhp[(size_t)(kt << 1) << 10];
        const float rh1 = rhp[(size_t)((kt << 1) + 1) << 10];

        // ---- swapped QK^T: S^T[key][q], 2 key-blocks ----
        f32x16 sc[2];
        #pragma unroll
        for (int i = 0; i < 16; ++i) { sc[0][i] = 0.f; sc[1][i] = 0.f; }
        #pragma unroll
        for (int c = 0; c < 4; ++c) {
            const int ch = ((c << 1) + g) ^ swz;
            const bf16x8 ka0 = *(const bf16x8*)&Kl[q5 * 64 + ch * 8];
            const bf16x8 ka1 = *(const bf16x8*)&Kl[(32 + q5) * 64 + ch * 8];
            sc[0] = __builtin_amdgcn_mfma_f32_32x32x16_bf16(ka0, qf[c], sc[0], 0, 0, 0);
            sc[1] = __builtin_amdgcn_mfma_f32_32x32x16_bf16(ka1, qf[c], sc[1], 0, 0, 0);
        }

        // ---- bias + exp (no max shift), pack to bf16 pairs ----
        unsigned pkA[2][4], pkB[2][4];
        #pragma unroll
        for (int cb = 0; cb < 2; ++cb) {
            const float rh = cb ? rh1 : rh0;
            #pragma unroll
            for (int m = 0; m < 4; ++m) {
                const float e0 = __expf(fmaf(sc[cb][4 * m + 0], 0.125f, rh + rw16[4 * m + 0]));
                const float e1 = __expf(fmaf(sc[cb][4 * m + 1], 0.125f, rh + rw16[4 * m + 1]));
                const float e2 = __expf(fmaf(sc[cb][4 * m + 2], 0.125f, rh + rw16[4 * m + 2]));
                const float e3 = __expf(fmaf(sc[cb][4 * m + 3], 0.125f, rh + rw16[4 * m + 3]));
                lsum += (e0 + e1) + (e2 + e3);
                pkA[cb][m] = pk2bf(e0, e1);
                pkB[cb][m] = pk2bf(e2, e3);
            }
        }

        // ---- PV: O^T += mfma(V^T, P^T); P-frags via permlane32_swap ----
        #pragma unroll
        for (int kc = 0; kc < 4; ++kc) {
            const int cb = kc >> 1, hf = kc & 1;
            const u32x2 sA = __builtin_amdgcn_permlane32_swap(
                pkA[cb][2 * hf], pkA[cb][2 * hf + 1], false, false);
            const u32x2 sB = __builtin_amdgcn_permlane32_swap(
                pkB[cb][2 * hf], pkB[cb][2 * hf + 1], false, false);
            const bf16x8 pf = mk_bf16x8(sA[0], sB[0], sA[1], sB[1]);
            const int ch = ((kc << 1) + g) ^ swz;
            const bf16x8 va0 = *(const bf16x8*)&Vt[q5 * 64 + ch * 8];
            const bf16x8 va1 = *(const bf16x8*)&Vt[(32 + q5) * 64 + ch * 8];
            oc[0] = __builtin_amdgcn_mfma_f32_32x32x16_bf16(va0, pf, oc[0], 0, 0, 0);
            oc[1] = __builtin_amdgcn_mfma_f32_32x32x16_bf16(va1, pf, oc[1], 0, 0, 0);
        }
        __syncthreads();
    }

    // ---- normalize ----
    lsum += __shfl_xor(lsum, 32);
    const float inv = 1.f / lsum;

    // ---- O^T -> O via wave-private LDS bounce (reuse KV), coalesced store ----
    unsigned* bw = (unsigned*)&KV[0][0];      // [64 rows][34 u32] (stride-34 pad)
    unsigned* myrow = bw + (w * 32 + q5) * 34;
    #pragma unroll
    for (int db = 0; db < 2; ++db)
        #pragma unroll
        for (int k = 0; k < 8; ++k) {
            const int d = ((2 * k) & 3) + ((k >> 1) << 3) + (g << 2) + (db << 5);
            myrow[d >> 1] = pk2bf(oc[db][2 * k] * inv, oc[db][2 * k + 1] * inv);
        }

    const int bi = bn / NHD, hn = bn - bi * NHD;
    const int c8 = l & 7;
    #pragma unroll
    for (int i = 0; i < 4; ++i) {
        const int row = w * 32 + (i << 3) + rsub;
        const unsigned* rp = bw + row * 34 + (c8 << 2);
        const uint2 xa = *(const uint2*)rp;
        const uint2 xb = *(const uint2*)(rp + 2);
        int4 o; o.x = (int)xa.x; o.y = (int)xa.y; o.z = (int)xb.x; o.w = (int)xb.y;
        *(int4*)(abf2 + ((size_t)hn * 4096 + ((size_t)bi << 10) + q0 + row) * 64 + (c8 << 3)) = o;
    }
}

// ---------------- output projection: bf16 MFMA GEMM, 2-phase dbuf -------------
__global__ __launch_bounds__(256, 2) void proj_mfma(
    const ushort* __restrict__ abf2, const ushort* __restrict__ pwbf2,
    const float* __restrict__ pb, float* __restrict__ out)
{
    __shared__ __align__(16) ushort Sp[32768];

    const int t = threadIdx.x;
    const int w = t >> 6, l = t & 63;
    const int lr = l & 15, lg = l >> 4;
    const int n0 = blockIdx.x << 7;
    const int m0 = blockIdx.y << 7;

    const int srow = (w << 3) + (l >> 3);
    const int scol = (l & 7) << 3;
    const ushort* Agl = abf2 + (size_t)(m0 + srow) * 64 + scol;
    const ushort* Bgl = pwbf2 + (size_t)(n0 + srow) * 64 + scol;

    f32x4 acc[4][4];
    #pragma unroll
    for (int mi = 0; mi < 4; ++mi)
        #pragma unroll
        for (int ni = 0; ni < 4; ++ni) acc[mi][ni] = (f32x4){0.f, 0.f, 0.f, 0.f};

    const int mb = (w >> 1) << 6, nb = (w & 1) << 6;

    #pragma unroll
    for (int i = 0; i < 4; ++i) {
        gload_lds16(Agl + (size_t)(i << 5) * 64, &Sp[(i << 11) + (w << 9)]);
        gload_lds16(Bgl + (size_t)(i << 5) * 64, &Sp[8192 + (i << 11) + (w << 9)]);
    }
    __syncthreads();

    for (int kt = 0; kt < 12; ++kt) {
        const int cb = (kt & 1) << 14;
        if (kt < 11) {
            const int nbuf = ((kt + 1) & 1) << 14;
            #pragma unroll
            for (int i = 0; i < 4; ++i) {
                gload_lds16(Agl + ((size_t)(kt + 1) * 4096 + (i << 5)) * 64,
                            &Sp[nbuf + (i << 11) + (w << 9)]);
                gload_lds16(Bgl + ((size_t)(kt + 1) * CD + (i << 5)) * 64,
                            &Sp[nbuf + 8192 + (i << 11) + (w << 9)]);
            }
        }
        #pragma unroll
        for (int kk = 0; kk < 2; ++kk) {
            bf16x8 af[4], bf[4];
            #pragma unroll
            for (int mi = 0; mi < 4; ++mi)
                af[mi] = *(const bf16x8*)&Sp[cb + (mb + (mi << 4) + lr) * 64 + (kk << 5) + (lg << 3)];
            #pragma unroll
            for (int ni = 0; ni < 4; ++ni)
                bf[ni] = *(const bf16x8*)&Sp[cb + 8192 + (nb + (ni << 4) + lr) * 64 + (kk << 5) + (lg << 3)];
            #pragma unroll
            for (int mi = 0; mi < 4; ++mi)
                #pragma unroll
                for (int ni = 0; ni < 4; ++ni)
                    acc[mi][ni] = __builtin_amdgcn_mfma_f32_16x16x32_bf16(af[mi], bf[ni], acc[mi][ni], 0, 0, 0);
        }
        __syncthreads();
    }

    float bl[4];
    #pragma unroll
    for (int ni = 0; ni < 4; ++ni) bl[ni] = pb[n0 + nb + (ni << 4) + lr];
    #pragma unroll
    for (int mi = 0; mi < 4; ++mi)
        #pragma unroll
        for (int ni = 0; ni < 4; ++ni)
            #pragma unroll
            for (int reg = 0; reg < 4; ++reg)
                out[(size_t)(m0 + mb + (mi << 4) + (lg << 2) + reg) * CD
                    + n0 + nb + (ni << 4) + lr] = acc[mi][ni][reg] + bl[ni];
}

extern "C" void kernel_launch(void* const* d_in, const int* in_sizes, int n_in,
                              void* d_out, int out_size, void* d_ws, size_t ws_size,
                              hipStream_t stream) {
    (void)in_sizes; (void)n_in; (void)out_size; (void)ws_size;
    const float* x   = (const float*)d_in[0];
    const float* Wq  = (const float*)d_in[1];
    const float* Wk  = (const float*)d_in[2];
    const float* Wv  = (const float*)d_in[3];
    const float* bq  = (const float*)d_in[4];
    const float* bk  = (const float*)d_in[5];
    const float* bv  = (const float*)d_in[6];
    const float* rph = (const float*)d_in[7];
    const float* rpw = (const float*)d_in[8];
    const float* pw  = (const float*)d_in[9];
    const float* pb  = (const float*)d_in[10];
    float* out = (float*)d_out;

    ushort* cvt  = (ushort*)d_ws;
    ushort* xbf  = cvt;
    ushort* wqbf = cvt + 3145728;
    ushort* wkbf = wqbf + 589824;
    ushort* wvbf = wkbf + 589824;
    ushort* pwbf = wvbf + 589824;      // panel layout [k/64][768][64]
    ushort* qbf  = pwbf + 589824;
    ushort* kbf  = qbf  + 3145728;
    ushort* vbfT = kbf  + 3145728;
    ushort* abf2 = vbfT + 3145728;     // [head][4096][64]
    float*  rhb3 = (float*)(abf2 + 3145728);   // [bn][k2 32][s 1024]
    float*  rwb2 = rhb3 + 1572864;             // [bn][s][32] reg-permuted

    hipLaunchKernelGGL(cvt_bf16_k, dim3(5376), dim3(256), 0, stream,
                       x, Wq, Wk, Wv, pw, cvt);
    hipLaunchKernelGGL(qkv_mfma, dim3(18, 32), dim3(256), 0, stream,
                       xbf, wqbf, wkbf, wvbf, bq, bk, bv, qbf, kbf, vbfT);
    hipLaunchKernelGGL(rel_kernel, dim3(32, 48), dim3(256), 0, stream,
                       qbf, rph, rpw, rhb3, rwb2);
    hipLaunchKernelGGL(attn_mfma, dim3(16, 48), dim3(128), 0, stream,
                       qbf, kbf, vbfT, rhb3, rwb2, abf2);
    hipLaunchKernelGGL(proj_mfma, dim3(6, 32), dim3(256), 0, stream,
                       abf2, pwbf, pb, out);
}

// Round 11
// 98.472 us; speedup vs baseline: 1.1543x; 1.1543x over previous
//
#include <hip/hip_runtime.h>
#include <hip/hip_bf16.h>
#include <math.h>

typedef float4 f4;
typedef __attribute__((ext_vector_type(8))) short bf16x8;
typedef __attribute__((ext_vector_type(4))) float f32x4;
typedef __attribute__((ext_vector_type(16))) float f32x16;

#define CD   768
#define SEQ  1024
#define NHD  12
#define DH   64

__device__ __forceinline__ ushort f2bf(float x) {
    union { __hip_bfloat16 h; ushort u; } v;
    v.h = __float2bfloat16(x);
    return v.u;
}
__device__ __forceinline__ unsigned pk2bf(float a, float b) {
    union { __hip_bfloat162 h; unsigned u; } v;
    v.h = __float22bfloat162_rn(make_float2(a, b));
    return v.u;
}
__device__ __forceinline__ void gload_lds16(const ushort* g, ushort* l) {
    __builtin_amdgcn_global_load_lds((const __attribute__((address_space(1))) void*)g,
                                     (__attribute__((address_space(3))) void*)l, 16, 0, 0);
}

// ---------------- fp32 -> bf16 conversion pre-pass ---------------------------
// x, Wq, Wk, Wv -> row-major bf16; pw -> panel layout [k/64][n][k%64]
__global__ __launch_bounds__(256) void cvt_bf16_k(
    const float* __restrict__ x, const float* __restrict__ Wq,
    const float* __restrict__ Wk, const float* __restrict__ Wv,
    const float* __restrict__ pw, ushort* __restrict__ dst)
{
    const int idx = blockIdx.x * 256 + threadIdx.x;
    if (idx >= 1376256) return;
    const int e = idx << 2;
    if (e < 4915200) {
        const float* src; int off;
        if      (e < 3145728) { src = x;  off = e; }
        else if (e < 3735552) { src = Wq; off = e - 3145728; }
        else if (e < 4325376) { src = Wk; off = e - 3735552; }
        else                  { src = Wv; off = e - 4325376; }
        const f4 v = *(const f4*)(src + off);
        uint2 o;
        o.x = pk2bf(v.x, v.y);
        o.y = pk2bf(v.z, v.w);
        *(uint2*)(dst + e) = o;
    } else {
        const int off = e - 4915200;          // pw linear = n*768 + k
        const int n = off / CD, k = off - n * CD;
        const f4 v = *(const f4*)(pw + off);
        uint2 o;
        o.x = pk2bf(v.x, v.y);
        o.y = pk2bf(v.z, v.w);
        *(uint2*)(dst + 4915200 + ((size_t)(k >> 6) * CD + n) * 64 + (k & 63)) = o;
    }
}

// ---------------- QKV projection: bf16 MFMA GEMM, 2-phase dbuf ----------------
__global__ __launch_bounds__(256, 2) void qkv_mfma(
    const ushort* __restrict__ xbf,
    const ushort* __restrict__ wq, const ushort* __restrict__ wk, const ushort* __restrict__ wv,
    const float* __restrict__ bq, const float* __restrict__ bk, const float* __restrict__ bv,
    ushort* __restrict__ qbf, ushort* __restrict__ kbf, ushort* __restrict__ vbfT)
{
    __shared__ __align__(16) ushort Sq[32768];   // buf b: A at b*16384, B at +8192

    const int t = threadIdx.x;
    const int w = t >> 6, l = t & 63;
    const int lr = l & 15, lg = l >> 4;
    const int n0 = blockIdx.x << 7;
    const int m0 = blockIdx.y << 7;
    const int sel  = n0 / CD;
    const int nloc = n0 % CD;
    const ushort* Wb  = (sel == 0) ? wq : ((sel == 1) ? wk : wv);
    const float* bias = (sel == 0) ? bq : ((sel == 1) ? bk : bv);

    const int srow = (w << 3) + (l >> 3);
    const int scol = (l & 7) << 3;
    const ushort* Agl = xbf + (size_t)(m0 + srow) * CD + scol;
    const ushort* Bgl = Wb + (size_t)(nloc + srow) * CD + scol;

    f32x4 acc[4][4];
    #pragma unroll
    for (int mi = 0; mi < 4; ++mi)
        #pragma unroll
        for (int ni = 0; ni < 4; ++ni) acc[mi][ni] = (f32x4){0.f, 0.f, 0.f, 0.f};

    const int mb = (w >> 1) << 6, nb = (w & 1) << 6;

    // prologue: stage K-step 0 into buf 0
    #pragma unroll
    for (int i = 0; i < 4; ++i) {
        gload_lds16(Agl + (size_t)(i << 5) * CD, &Sq[(i << 11) + (w << 9)]);
        gload_lds16(Bgl + (size_t)(i << 5) * CD, &Sq[8192 + (i << 11) + (w << 9)]);
    }
    __syncthreads();

    for (int kt = 0; kt < 12; ++kt) {
        const int cb = (kt & 1) << 14;
        if (kt < 11) {
            const int nbuf = ((kt + 1) & 1) << 14;
            const int kc = (kt + 1) << 6;
            #pragma unroll
            for (int i = 0; i < 4; ++i) {
                gload_lds16(Agl + (size_t)(i << 5) * CD + kc, &Sq[nbuf + (i << 11) + (w << 9)]);
                gload_lds16(Bgl + (size_t)(i << 5) * CD + kc, &Sq[nbuf + 8192 + (i << 11) + (w << 9)]);
            }
        }
        #pragma unroll
        for (int kk = 0; kk < 2; ++kk) {
            bf16x8 af[4], bf[4];
            #pragma unroll
            for (int mi = 0; mi < 4; ++mi)
                af[mi] = *(const bf16x8*)&Sq[cb + (mb + (mi << 4) + lr) * 64 + (kk << 5) + (lg << 3)];
            #pragma unroll
            for (int ni = 0; ni < 4; ++ni)
                bf[ni] = *(const bf16x8*)&Sq[cb + 8192 + (nb + (ni << 4) + lr) * 64 + (kk << 5) + (lg << 3)];
            #pragma unroll
            for (int mi = 0; mi < 4; ++mi)
                #pragma unroll
                for (int ni = 0; ni < 4; ++ni)
                    acc[mi][ni] = __builtin_amdgcn_mfma_f32_16x16x32_bf16(af[mi], bf[ni], acc[mi][ni], 0, 0, 0);
        }
        __syncthreads();
    }

    ushort* Ep = Sq + (w << 12);

    float bl[4];
    #pragma unroll
    for (int ni = 0; ni < 4; ++ni) bl[ni] = bias[nloc + nb + (ni << 4) + lr];

    if (sel < 2) {
        #pragma unroll
        for (int mi = 0; mi < 4; ++mi)
            #pragma unroll
            for (int ni = 0; ni < 4; ++ni)
                #pragma unroll
                for (int reg = 0; reg < 4; ++reg)
                    Ep[((mi << 4) + (lg << 2) + reg) * 64 + (ni << 4) + lr] =
                        f2bf(acc[mi][ni][reg] + bl[ni]);
    } else {
        // V: transpose + key-permute within 64-block
        #pragma unroll
        for (int mi = 0; mi < 4; ++mi)
            #pragma unroll
            for (int ni = 0; ni < 4; ++ni)
                #pragma unroll
                for (int reg = 0; reg < 4; ++reg)
                    Ep[((ni << 4) + lr) * 64 + (lg << 4) + (reg << 2) + mi] =
                        f2bf(acc[mi][ni][reg] + bl[ni]);
    }

    const int bi   = m0 >> 10;
    const int si0  = (m0 & 1023) + mb;
    const int head = (nloc + nb) >> 6;
    const int bn   = bi * NHD + head;
    const ushort* src = Ep + l * 64;
    if (sel < 2) {
        ushort* dbf = (sel == 0) ? qbf : kbf;
        ushort* dst = dbf + (((size_t)bn << 10) + si0 + l) * 64;
        #pragma unroll
        for (int c = 0; c < 8; ++c)
            *(bf16x8*)(dst + (c << 3)) = *(const bf16x8*)(src + (c << 3));
    } else {
        ushort* dst = vbfT + (((size_t)(bn * DH + l)) << 10) + si0;
        #pragma unroll
        for (int c = 0; c < 8; ++c)
            *(bf16x8*)(dst + (c << 3)) = *(const bf16x8*)(src + (c << 3));
    }
}

// ---------------- rel-pos bias tables via MFMA --------------------------------
// 4 waves/block, wave = one h value (32 q-rows). rel_h = mfma(Rh-rev, q) 32x32x64;
// rel_w = mfma(Rw, q) 64x32x64 + diagonal-band gather via per-wave LDS.
// Outputs: rhb2[bn][qt][ktp(16)][row64][2], rwb[bn][s][32] (R9 attn layouts).
__global__ __launch_bounds__(256, 4) void rel_kernel(
    const ushort* __restrict__ qbf, const float* __restrict__ rph,
    const float* __restrict__ rpw,
    float* __restrict__ rhb2, float* __restrict__ rwb)
{
    __shared__ float Pl[4][64][33];

    const int t = threadIdx.x;
    const int w = t >> 6, l = t & 63;
    const int q5 = l & 31, g = l >> 5;
    const int hq = blockIdx.x, bn = blockIdx.y;
    const int h = (hq << 2) + w;           // 0..31
    const int s = (h << 5) + q5;

    // Q B-fragments: col = q5, k-slot = g*8+j, chunk c -> d = c*16 + g*8 + j
    const ushort* qp = qbf + (((size_t)bn << 10) + s) * 64 + (g << 3);
    bf16x8 qf[4];
    #pragma unroll
    for (int c = 0; c < 4; ++c) qf[c] = *(const bf16x8*)(qp + (c << 4));

    // ---- rel_h: A row a=q5 -> table row h+31-q5 (rows h..h+31, max 62) ----
    f32x16 acch;
    #pragma unroll
    for (int i = 0; i < 16; ++i) acch[i] = 0.f;
    {
        const float* rp = rph + (size_t)(h + 31 - q5) * 64 + (g << 3);
        #pragma unroll
        for (int c = 0; c < 4; ++c) {
            const f4 v0 = *(const f4*)(rp + (c << 4));
            const f4 v1 = *(const f4*)(rp + (c << 4) + 4);
            union { unsigned u[4]; bf16x8 v; } u;
            u.u[0] = pk2bf(v0.x, v0.y); u.u[1] = pk2bf(v0.z, v0.w);
            u.u[2] = pk2bf(v1.x, v1.y); u.u[3] = pk2bf(v1.z, v1.w);
            acch = __builtin_amdgcn_mfma_f32_32x32x16_bf16(u.v, qf[c], acch, 0, 0, 0);
        }
    }
    // store rel_h: C row = k2 = (r&3)+8*(r>>2)+4g, col = q5 -> s
    {
        float* base = rhb2 + (((size_t)(bn * 16 + (h >> 1)) << 4) << 7)
                    + ((((h & 1) << 5) + q5) << 1);
        #pragma unroll
        for (int r = 0; r < 16; r += 2) {
            const int k2 = (r & 3) + ((r >> 2) << 3) + (g << 2);
            *(float2*)(base + ((size_t)(k2 >> 1) << 7)) = make_float2(acch[r], acch[r + 1]);
        }
    }

    // ---- rel_w: P[r][q] = Rw[r] . q, r = 0..62 (2 row-blocks, row 63 zeroed) --
    f32x16 accw[2];
    #pragma unroll
    for (int i = 0; i < 16; ++i) { accw[0][i] = 0.f; accw[1][i] = 0.f; }
    #pragma unroll
    for (int b = 0; b < 2; ++b) {
        const int r = (b << 5) + q5;
        const bool ok = (r < 63);
        const float* rp = rpw + (size_t)r * 64 + (g << 3);
        #pragma unroll
        for (int c = 0; c < 4; ++c) {
            union { unsigned u[4]; bf16x8 v; } u;
            if (ok) {
                const f4 v0 = *(const f4*)(rp + (c << 4));
                const f4 v1 = *(const f4*)(rp + (c << 4) + 4);
                u.u[0] = pk2bf(v0.x, v0.y); u.u[1] = pk2bf(v0.z, v0.w);
                u.u[2] = pk2bf(v1.x, v1.y); u.u[3] = pk2bf(v1.z, v1.w);
            } else {
                u.u[0] = 0u; u.u[1] = 0u; u.u[2] = 0u; u.u[3] = 0u;
            }
            accw[b] = __builtin_amdgcn_mfma_f32_32x32x16_bf16(u.v, qf[c], accw[b], 0, 0, 0);
        }
    }
    // P -> per-wave LDS tile
    #pragma unroll
    for (int b = 0; b < 2; ++b)
        #pragma unroll
        for (int r = 0; r < 16; ++r) {
            const int row = (r & 3) + ((r >> 2) << 3) + (g << 2) + (b << 5);
            Pl[w][row][q5] = accw[b][r];
        }
    __syncthreads();
    // gather band: rel_w[s][k2] = P[q5+31-k2][q5]; lane covers k2 = g*16 + 0..15
    float ow[16];
    #pragma unroll
    for (int i = 0; i < 16; ++i) {
        const int k2 = (g << 4) + i;
        ow[i] = Pl[w][q5 + 31 - k2][q5];
    }
    float* wb = rwb + ((((size_t)bn << 10) + s) << 5) + (g << 4);
    #pragma unroll
    for (int i = 0; i < 4; ++i) {
        f4 v; v.x = ow[4*i]; v.y = ow[4*i+1]; v.z = ow[4*i+2]; v.w = ow[4*i+3];
        *(f4*)(wb + (i << 2)) = v;
    }
}

// ---------------- MFMA flash attention, 2-phase K/V double-buffer -------------
// 64 q-rows/block (grid 768, 3 blocks/CU). Stage NEXT K/V tile before computing
// current; ONE barrier per tile (vmcnt drain overlapped with compute).
__global__ __launch_bounds__(256, 3) void attn_mfma(
    const ushort* __restrict__ qbf, const ushort* __restrict__ kbf,
    const ushort* __restrict__ vbfT,
    const float* __restrict__ rhb2, const float* __restrict__ rwb,
    ushort* __restrict__ abf2)
{
    __shared__ __align__(16) ushort KV[2][8192];  // [buf][ K:0..4095 | V:4096.. ]
    __shared__ __align__(16) ushort Pl[4][16][72];

    const int t  = threadIdx.x;
    const int l  = t & 63, w = t >> 6;
    const int lr = l & 15, lg = l >> 4;
    const int qt = blockIdx.x, bn = blockIdx.y;
    const int q0 = qt << 6;

    const ushort* qp = qbf + (((size_t)bn << 10) + q0 + w * 16 + lr) * DH + lg * 8;
    const bf16x8 qa0 = *(const bf16x8*)qp;
    const bf16x8 qa1 = *(const bf16x8*)(qp + 32);

    float rw_[4][2];
    #pragma unroll
    for (int reg = 0; reg < 4; ++reg) {
        const size_t rrow = ((size_t)bn << 10) + q0 + w * 16 + lg * 4 + reg;
        rw_[reg][0] = rwb[(rrow << 5) + lr];
        rw_[reg][1] = rwb[(rrow << 5) + 16 + lr];
    }
    const float* rhbase = rhb2 + (size_t)(bn * 16 + qt) * 2048 + (w * 16 + lg * 4) * 2;

    // staging geometry (proven R7 structure, dbuf dest)
    const int i0   = w << 1;
    const int rsub = l >> 3;
    const int coff = ((l & 7) ^ rsub) << 3;
    const size_t kbase = ((size_t)bn << 16);
    const ushort* kp0 = kbf + kbase + (size_t)((i0 << 3) + rsub) * 64 + coff;
    const ushort* kp1 = kp0 + 512;
    const ushort* vp0 = vbfT + kbase + ((size_t)((i0 << 3) + rsub) << 10) + coff;
    const ushort* vp1 = vp0 + 8192;
    const int lds0 = i0 << 9;

    f32x4 oc[4];
    #pragma unroll
    for (int nf = 0; nf < 4; ++nf) oc[nf] = (f32x4){0.f, 0.f, 0.f, 0.f};
    f32x4 sumc = (f32x4){0.f, 0.f, 0.f, 0.f};
    bf16x8 ones;
    #pragma unroll
    for (int i = 0; i < 8; ++i) ones[i] = (short)0x3F80;   // bf16 1.0

    const int s0c = lg ^ (lr & 7);   // swizzled 16B-chunk index for reads

    // prologue: stage tile 0 into buf 0
    gload_lds16(kp0, &KV[0][lds0]);
    gload_lds16(kp1, &KV[0][lds0 + 512]);
    gload_lds16(vp0, &KV[0][4096 + lds0]);
    gload_lds16(vp1, &KV[0][4096 + lds0 + 512]);
    __syncthreads();

    for (int kt = 0; kt < 16; ++kt) {
        const int cur = kt & 1;
        if (kt < 15) {
            ushort* nb_ = &KV[cur ^ 1][0];
            gload_lds16(kp0 + ((kt + 1) << 12), nb_ + lds0);
            gload_lds16(kp1 + ((kt + 1) << 12), nb_ + lds0 + 512);
            gload_lds16(vp0 + ((kt + 1) << 6), nb_ + 4096 + lds0);
            gload_lds16(vp1 + ((kt + 1) << 6), nb_ + 4096 + lds0 + 512);
        }
        const ushort* Kl = &KV[cur][0];
        const ushort* Vt = &KV[cur][4096];
        const f4 rh01 = *(const f4*)(rhbase + (kt << 7));
        const f4 rh23 = *(const f4*)(rhbase + (kt << 7) + 4);

        // ---- QK^T: S[16q x 64key] per wave ----
        f32x4 sc[4];
        #pragma unroll
        for (int f = 0; f < 4; ++f) {
            f32x4 c = (f32x4){0.f, 0.f, 0.f, 0.f};
            const int rb = (f * 16 + lr) * 64;
            const bf16x8 kb0 = *(const bf16x8*)&Kl[rb + (s0c << 3)];
            const bf16x8 kb1 = *(const bf16x8*)&Kl[rb + ((s0c ^ 4) << 3)];
            c = __builtin_amdgcn_mfma_f32_16x16x32_bf16(qa0, kb0, c, 0, 0, 0);
            c = __builtin_amdgcn_mfma_f32_16x16x32_bf16(qa1, kb1, c, 0, 0, 0);
            sc[f] = c;
        }

        // ---- bias + exp (no max shift), pack P (key' = lr*4+f) ----
        #pragma unroll
        for (int reg = 0; reg < 4; ++reg) {
            const float rhx = (reg == 0) ? rh01.x : (reg == 1) ? rh01.z
                             : (reg == 2) ? rh23.x : rh23.z;
            const float rhy = (reg == 0) ? rh01.y : (reg == 1) ? rh01.w
                             : (reg == 2) ? rh23.y : rh23.w;
            const float e0 = __expf(fmaf(sc[0][reg], 0.125f, rhx + rw_[reg][0]));
            const float e1 = __expf(fmaf(sc[1][reg], 0.125f, rhx + rw_[reg][1]));
            const float e2 = __expf(fmaf(sc[2][reg], 0.125f, rhy + rw_[reg][0]));
            const float e3 = __expf(fmaf(sc[3][reg], 0.125f, rhy + rw_[reg][1]));
            uint2 pk;
            pk.x = pk2bf(e0, e1);
            pk.y = pk2bf(e2, e3);
            *(uint2*)&Pl[w][lg * 4 + reg][lr * 4] = pk;
        }

        // ---- P frags, row-sum MFMA, PV ----
        const bf16x8 pa0 = *(const bf16x8*)&Pl[w][lr][lg * 8];
        const bf16x8 pa1 = *(const bf16x8*)&Pl[w][lr][lg * 8 + 32];
        sumc = __builtin_amdgcn_mfma_f32_16x16x32_bf16(pa0, ones, sumc, 0, 0, 0);
        sumc = __builtin_amdgcn_mfma_f32_16x16x32_bf16(pa1, ones, sumc, 0, 0, 0);
        #pragma unroll
        for (int nf = 0; nf < 4; ++nf) {
            const int rb = (nf * 16 + lr) * 64;
            const bf16x8 vb0 = *(const bf16x8*)&Vt[rb + (s0c << 3)];
            const bf16x8 vb1 = *(const bf16x8*)&Vt[rb + ((s0c ^ 4) << 3)];
            oc[nf] = __builtin_amdgcn_mfma_f32_16x16x32_bf16(pa0, vb0, oc[nf], 0, 0, 0);
            oc[nf] = __builtin_amdgcn_mfma_f32_16x16x32_bf16(pa1, vb1, oc[nf], 0, 0, 0);
        }
        __syncthreads();
    }

    // ---- normalize, write abf2[head][4096][64] -------------------------------
    const int bi = bn / NHD, hn = bn - bi * NHD;
    #pragma unroll
    for (int reg = 0; reg < 4; ++reg) {
        const float inv = 1.f / sumc[reg];
        const int row = q0 + w * 16 + lg * 4 + reg;
        ushort* dst = abf2 + ((size_t)hn * 4096 + (bi << 10) + row) * 64 + lr;
        union { unsigned u; ushort2 s2; } a, b;
        a.u = pk2bf(oc[0][reg] * inv, oc[1][reg] * inv);
        b.u = pk2bf(oc[2][reg] * inv, oc[3][reg] * inv);
        dst[0]  = a.s2.x;
        dst[16] = a.s2.y;
        dst[32] = b.s2.x;
        dst[48] = b.s2.y;
    }
}

// ---------------- output projection: bf16 MFMA GEMM, 2-phase dbuf -------------
// A = abf2 [panel p][4096][64]; B = pwbf2 [panel][768][64]; BK=64.
__global__ __launch_bounds__(256, 2) void proj_mfma(
    const ushort* __restrict__ abf2, const ushort* __restrict__ pwbf2,
    const float* __restrict__ pb, float* __restrict__ out)
{
    __shared__ __align__(16) ushort Sp[32768];   // buf b: A at b*16384, B at +8192

    const int t = threadIdx.x;
    const int w = t >> 6, l = t & 63;
    const int lr = l & 15, lg = l >> 4;
    const int n0 = blockIdx.x << 7;
    const int m0 = blockIdx.y << 7;

    const int srow = (w << 3) + (l >> 3);
    const int scol = (l & 7) << 3;
    const ushort* Agl = abf2 + (size_t)(m0 + srow) * 64 + scol;   // + p*4096*64
    const ushort* Bgl = pwbf2 + (size_t)(n0 + srow) * 64 + scol;  // + p*768*64

    f32x4 acc[4][4];
    #pragma unroll
    for (int mi = 0; mi < 4; ++mi)
        #pragma unroll
        for (int ni = 0; ni < 4; ++ni) acc[mi][ni] = (f32x4){0.f, 0.f, 0.f, 0.f};

    const int mb = (w >> 1) << 6, nb = (w & 1) << 6;

    #pragma unroll
    for (int i = 0; i < 4; ++i) {
        gload_lds16(Agl + (size_t)(i << 5) * 64, &Sp[(i << 11) + (w << 9)]);
        gload_lds16(Bgl + (size_t)(i << 5) * 64, &Sp[8192 + (i << 11) + (w << 9)]);
    }
    __syncthreads();

    for (int kt = 0; kt < 12; ++kt) {
        const int cb = (kt & 1) << 14;
        if (kt < 11) {
            const int nbuf = ((kt + 1) & 1) << 14;
            #pragma unroll
            for (int i = 0; i < 4; ++i) {
                gload_lds16(Agl + ((size_t)(kt + 1) * 4096 + (i << 5)) * 64,
                            &Sp[nbuf + (i << 11) + (w << 9)]);
                gload_lds16(Bgl + ((size_t)(kt + 1) * CD + (i << 5)) * 64,
                            &Sp[nbuf + 8192 + (i << 11) + (w << 9)]);
            }
        }
        #pragma unroll
        for (int kk = 0; kk < 2; ++kk) {
            bf16x8 af[4], bf[4];
            #pragma unroll
            for (int mi = 0; mi < 4; ++mi)
                af[mi] = *(const bf16x8*)&Sp[cb + (mb + (mi << 4) + lr) * 64 + (kk << 5) + (lg << 3)];
            #pragma unroll
            for (int ni = 0; ni < 4; ++ni)
                bf[ni] = *(const bf16x8*)&Sp[cb + 8192 + (nb + (ni << 4) + lr) * 64 + (kk << 5) + (lg << 3)];
            #pragma unroll
            for (int mi = 0; mi < 4; ++mi)
                #pragma unroll
                for (int ni = 0; ni < 4; ++ni)
                    acc[mi][ni] = __builtin_amdgcn_mfma_f32_16x16x32_bf16(af[mi], bf[ni], acc[mi][ni], 0, 0, 0);
        }
        __syncthreads();
    }

    float bl[4];
    #pragma unroll
    for (int ni = 0; ni < 4; ++ni) bl[ni] = pb[n0 + nb + (ni << 4) + lr];
    #pragma unroll
    for (int mi = 0; mi < 4; ++mi)
        #pragma unroll
        for (int ni = 0; ni < 4; ++ni)
            #pragma unroll
            for (int reg = 0; reg < 4; ++reg)
                out[(size_t)(m0 + mb + (mi << 4) + (lg << 2) + reg) * CD
                    + n0 + nb + (ni << 4) + lr] = acc[mi][ni][reg] + bl[ni];
}

extern "C" void kernel_launch(void* const* d_in, const int* in_sizes, int n_in,
                              void* d_out, int out_size, void* d_ws, size_t ws_size,
                              hipStream_t stream) {
    (void)in_sizes; (void)n_in; (void)out_size; (void)ws_size;
    const float* x   = (const float*)d_in[0];
    const float* Wq  = (const float*)d_in[1];
    const float* Wk  = (const float*)d_in[2];
    const float* Wv  = (const float*)d_in[3];
    const float* bq  = (const float*)d_in[4];
    const float* bk  = (const float*)d_in[5];
    const float* bv  = (const float*)d_in[6];
    const float* rph = (const float*)d_in[7];
    const float* rpw = (const float*)d_in[8];
    const float* pw  = (const float*)d_in[9];
    const float* pb  = (const float*)d_in[10];
    float* out = (float*)d_out;

    ushort* cvt  = (ushort*)d_ws;
    ushort* xbf  = cvt;
    ushort* wqbf = cvt + 3145728;
    ushort* wkbf = wqbf + 589824;
    ushort* wvbf = wkbf + 589824;
    ushort* pwbf = wvbf + 589824;      // panel layout [k/64][768][64]
    ushort* qbf  = pwbf + 589824;
    ushort* kbf  = qbf  + 3145728;
    ushort* vbfT = kbf  + 3145728;
    ushort* abf2 = vbfT + 3145728;     // [head][4096][64]
    float*  rhb2 = (float*)(abf2 + 3145728);   // [bn][qt][ktp][row64][2]
    float*  rwb  = rhb2 + 1572864;             // [bn][s][32]

    hipLaunchKernelGGL(cvt_bf16_k, dim3(5376), dim3(256), 0, stream,
                       x, Wq, Wk, Wv, pw, cvt);
    hipLaunchKernelGGL(qkv_mfma, dim3(18, 32), dim3(256), 0, stream,
                       xbf, wqbf, wkbf, wvbf, bq, bk, bv, qbf, kbf, vbfT);
    hipLaunchKernelGGL(rel_kernel, dim3(8, 48), dim3(256), 0, stream,
                       qbf, rph, rpw, rhb2, rwb);
    hipLaunchKernelGGL(attn_mfma, dim3(16, 48), dim3(256), 0, stream,
                       qbf, kbf, vbfT, rhb2, rwb, abf2);
    hipLaunchKernelGGL(proj_mfma, dim3(6, 32), dim3(256), 0, stream,
                       abf2, pwbf, pb, out);
}

// Round 12
// 88.830 us; speedup vs baseline: 1.2796x; 1.1085x over previous
//
#include <hip/hip_runtime.h>
#include <hip/hip_bf16.h>
#include <math.h>

typedef float4 f4;
typedef __attribute__((ext_vector_type(8))) short bf16x8;
typedef __attribute__((ext_vector_type(4))) float f32x4;
typedef __attribute__((ext_vector_type(16))) float f32x16;

#define CD   768
#define SEQ  1024
#define NHD  12
#define DH   64

__device__ __forceinline__ ushort f2bf(float x) {
    union { __hip_bfloat16 h; ushort u; } v;
    v.h = __float2bfloat16(x);
    return v.u;
}
__device__ __forceinline__ unsigned pk2bf(float a, float b) {
    union { __hip_bfloat162 h; unsigned u; } v;
    v.h = __float22bfloat162_rn(make_float2(a, b));
    return v.u;
}
__device__ __forceinline__ void gload_lds16(const ushort* g, ushort* l) {
    __builtin_amdgcn_global_load_lds((const __attribute__((address_space(1))) void*)g,
                                     (__attribute__((address_space(3))) void*)l, 16, 0, 0);
}

// ---------------- fp32 -> bf16 conversion pre-pass ---------------------------
// x, Wq, Wk, Wv -> row-major bf16; pw -> panel layout [k/64][n][k%64]
__global__ __launch_bounds__(256) void cvt_bf16_k(
    const float* __restrict__ x, const float* __restrict__ Wq,
    const float* __restrict__ Wk, const float* __restrict__ Wv,
    const float* __restrict__ pw, ushort* __restrict__ dst)
{
    const int idx = blockIdx.x * 256 + threadIdx.x;
    if (idx >= 1376256) return;
    const int e = idx << 2;
    if (e < 4915200) {
        const float* src; int off;
        if      (e < 3145728) { src = x;  off = e; }
        else if (e < 3735552) { src = Wq; off = e - 3145728; }
        else if (e < 4325376) { src = Wk; off = e - 3735552; }
        else                  { src = Wv; off = e - 4325376; }
        const f4 v = *(const f4*)(src + off);
        uint2 o;
        o.x = pk2bf(v.x, v.y);
        o.y = pk2bf(v.z, v.w);
        *(uint2*)(dst + e) = o;
    } else {
        const int off = e - 4915200;          // pw linear = n*768 + k
        const int n = off / CD, k = off - n * CD;
        const f4 v = *(const f4*)(pw + off);
        uint2 o;
        o.x = pk2bf(v.x, v.y);
        o.y = pk2bf(v.z, v.w);
        *(uint2*)(dst + 4915200 + ((size_t)(k >> 6) * CD + n) * 64 + (k & 63)) = o;
    }
}

// ---------------- QKV projection: bf16 MFMA GEMM, 2-phase dbuf ----------------
__global__ __launch_bounds__(256, 2) void qkv_mfma(
    const ushort* __restrict__ xbf,
    const ushort* __restrict__ wq, const ushort* __restrict__ wk, const ushort* __restrict__ wv,
    const float* __restrict__ bq, const float* __restrict__ bk, const float* __restrict__ bv,
    ushort* __restrict__ qbf, ushort* __restrict__ kbf, ushort* __restrict__ vbfT)
{
    __shared__ __align__(16) ushort Sq[32768];   // buf b: A at b*16384, B at +8192

    const int t = threadIdx.x;
    const int w = t >> 6, l = t & 63;
    const int lr = l & 15, lg = l >> 4;
    const int n0 = blockIdx.x << 7;
    const int m0 = blockIdx.y << 7;
    const int sel  = n0 / CD;
    const int nloc = n0 % CD;
    const ushort* Wb  = (sel == 0) ? wq : ((sel == 1) ? wk : wv);
    const float* bias = (sel == 0) ? bq : ((sel == 1) ? bk : bv);

    const int srow = (w << 3) + (l >> 3);
    const int scol = (l & 7) << 3;
    const ushort* Agl = xbf + (size_t)(m0 + srow) * CD + scol;
    const ushort* Bgl = Wb + (size_t)(nloc + srow) * CD + scol;

    f32x4 acc[4][4];
    #pragma unroll
    for (int mi = 0; mi < 4; ++mi)
        #pragma unroll
        for (int ni = 0; ni < 4; ++ni) acc[mi][ni] = (f32x4){0.f, 0.f, 0.f, 0.f};

    const int mb = (w >> 1) << 6, nb = (w & 1) << 6;

    // prologue: stage K-step 0 into buf 0
    #pragma unroll
    for (int i = 0; i < 4; ++i) {
        gload_lds16(Agl + (size_t)(i << 5) * CD, &Sq[(i << 11) + (w << 9)]);
        gload_lds16(Bgl + (size_t)(i << 5) * CD, &Sq[8192 + (i << 11) + (w << 9)]);
    }
    __syncthreads();

    for (int kt = 0; kt < 12; ++kt) {
        const int cb = (kt & 1) << 14;
        if (kt < 11) {
            const int nbuf = ((kt + 1) & 1) << 14;
            const int kc = (kt + 1) << 6;
            #pragma unroll
            for (int i = 0; i < 4; ++i) {
                gload_lds16(Agl + (size_t)(i << 5) * CD + kc, &Sq[nbuf + (i << 11) + (w << 9)]);
                gload_lds16(Bgl + (size_t)(i << 5) * CD + kc, &Sq[nbuf + 8192 + (i << 11) + (w << 9)]);
            }
        }
        #pragma unroll
        for (int kk = 0; kk < 2; ++kk) {
            bf16x8 af[4], bf[4];
            #pragma unroll
            for (int mi = 0; mi < 4; ++mi)
                af[mi] = *(const bf16x8*)&Sq[cb + (mb + (mi << 4) + lr) * 64 + (kk << 5) + (lg << 3)];
            #pragma unroll
            for (int ni = 0; ni < 4; ++ni)
                bf[ni] = *(const bf16x8*)&Sq[cb + 8192 + (nb + (ni << 4) + lr) * 64 + (kk << 5) + (lg << 3)];
            #pragma unroll
            for (int mi = 0; mi < 4; ++mi)
                #pragma unroll
                for (int ni = 0; ni < 4; ++ni)
                    acc[mi][ni] = __builtin_amdgcn_mfma_f32_16x16x32_bf16(af[mi], bf[ni], acc[mi][ni], 0, 0, 0);
        }
        __syncthreads();
    }

    ushort* Ep = Sq + (w << 12);

    float bl[4];
    #pragma unroll
    for (int ni = 0; ni < 4; ++ni) bl[ni] = bias[nloc + nb + (ni << 4) + lr];

    if (sel < 2) {
        #pragma unroll
        for (int mi = 0; mi < 4; ++mi)
            #pragma unroll
            for (int ni = 0; ni < 4; ++ni)
                #pragma unroll
                for (int reg = 0; reg < 4; ++reg)
                    Ep[((mi << 4) + (lg << 2) + reg) * 64 + (ni << 4) + lr] =
                        f2bf(acc[mi][ni][reg] + bl[ni]);
    } else {
        // V: transpose + key-permute within 64-block
        #pragma unroll
        for (int mi = 0; mi < 4; ++mi)
            #pragma unroll
            for (int ni = 0; ni < 4; ++ni)
                #pragma unroll
                for (int reg = 0; reg < 4; ++reg)
                    Ep[((ni << 4) + lr) * 64 + (lg << 4) + (reg << 2) + mi] =
                        f2bf(acc[mi][ni][reg] + bl[ni]);
    }

    const int bi   = m0 >> 10;
    const int si0  = (m0 & 1023) + mb;
    const int head = (nloc + nb) >> 6;
    const int bn   = bi * NHD + head;
    const ushort* src = Ep + l * 64;
    if (sel < 2) {
        ushort* dbf = (sel == 0) ? qbf : kbf;
        ushort* dst = dbf + (((size_t)bn << 10) + si0 + l) * 64;
        #pragma unroll
        for (int c = 0; c < 8; ++c)
            *(bf16x8*)(dst + (c << 3)) = *(const bf16x8*)(src + (c << 3));
    } else {
        ushort* dst = vbfT + (((size_t)(bn * DH + l)) << 10) + si0;
        #pragma unroll
        for (int c = 0; c < 8; ++c)
            *(bf16x8*)(dst + (c << 3)) = *(const bf16x8*)(src + (c << 3));
    }
}

// ---------------- MFMA flash attention + fused rel-pos prologue ---------------
// 64 q-rows/block (grid 768, 3 blocks/CU). Prologue computes the R11-verified
// MFMA rel tables for this block's 2 h-values directly into LDS (rhs_) and a
// scratch P-tile in the pre-staging KV buffer (rw hoisted to regs, then KV is
// reused). Main loop identical to R11 except rh reads come from LDS.
__global__ __launch_bounds__(256, 3) void attn_mfma(
    const ushort* __restrict__ qbf, const ushort* __restrict__ kbf,
    const ushort* __restrict__ vbfT,
    const float* __restrict__ rph, const float* __restrict__ rpw,
    ushort* __restrict__ abf2)
{
    __shared__ __align__(16) ushort KV[2][8192];  // [buf][ K:0..4095 | V:4096.. ]
    __shared__ __align__(16) ushort Pl[4][16][72];
    __shared__ __align__(16) float rhs_[2048];    // [ktp16][row64][2]

    const int t  = threadIdx.x;
    const int l  = t & 63, w = t >> 6;
    const int lr = l & 15, lg = l >> 4;
    const int qt = blockIdx.x, bn = blockIdx.y;
    const int q0 = qt << 6;

    // ======== rel prologue (R11 rel_kernel math, retargeted to LDS) ========
    {
        const int p   = w >> 1;           // h-pair index (0,1)
        const int sub = w & 1;            // sub-wave within pair
        const int h   = (qt << 1) + p;    // 0..31
        const int q5  = l & 31, g = l >> 5;

        // q B-frags for this h's 32 rows (R11-verified layout)
        const ushort* qp = qbf + (((size_t)bn << 10) + (h << 5) + q5) * 64 + (g << 3);
        bf16x8 qf[4];
        #pragma unroll
        for (int c = 0; c < 4; ++c) qf[c] = *(const bf16x8*)(qp + (c << 4));

        float* PwF = (float*)&KV[0][0] + p * 2112;   // [64][33] scratch

        if (sub == 0) {
            // ---- rel_h: mfma(Rh[h+31-q5], q) ----
            f32x16 acch;
            #pragma unroll
            for (int i = 0; i < 16; ++i) acch[i] = 0.f;
            {
                const float* rp = rph + (size_t)(h + 31 - q5) * 64 + (g << 3);
                #pragma unroll
                for (int c = 0; c < 4; ++c) {
                    const f4 v0 = *(const f4*)(rp + (c << 4));
                    const f4 v1 = *(const f4*)(rp + (c << 4) + 4);
                    union { unsigned u[4]; bf16x8 v; } u;
                    u.u[0] = pk2bf(v0.x, v0.y); u.u[1] = pk2bf(v0.z, v0.w);
                    u.u[2] = pk2bf(v1.x, v1.y); u.u[3] = pk2bf(v1.z, v1.w);
                    acch = __builtin_amdgcn_mfma_f32_32x32x16_bf16(u.v, qf[c], acch, 0, 0, 0);
                }
            }
            #pragma unroll
            for (int r = 0; r < 16; r += 2) {
                const int k2 = (r & 3) + ((r >> 2) << 3) + (g << 2);
                *(float2*)&rhs_[((k2 >> 1) << 7) + (((p << 5) + q5) << 1)] =
                    make_float2(acch[r], acch[r + 1]);
            }
            // ---- rel_w rows 0..31: mfma(Rw[q5], q) ----
            f32x16 accw;
            #pragma unroll
            for (int i = 0; i < 16; ++i) accw[i] = 0.f;
            {
                const float* rp = rpw + (size_t)q5 * 64 + (g << 3);
                #pragma unroll
                for (int c = 0; c < 4; ++c) {
                    const f4 v0 = *(const f4*)(rp + (c << 4));
                    const f4 v1 = *(const f4*)(rp + (c << 4) + 4);
                    union { unsigned u[4]; bf16x8 v; } u;
                    u.u[0] = pk2bf(v0.x, v0.y); u.u[1] = pk2bf(v0.z, v0.w);
                    u.u[2] = pk2bf(v1.x, v1.y); u.u[3] = pk2bf(v1.z, v1.w);
                    accw = __builtin_amdgcn_mfma_f32_32x32x16_bf16(u.v, qf[c], accw, 0, 0, 0);
                }
            }
            #pragma unroll
            for (int r = 0; r < 16; ++r) {
                const int row = (r & 3) + ((r >> 2) << 3) + (g << 2);
                PwF[row * 33 + q5] = accw[r];
            }
        } else {
            // ---- rel_w rows 32..62 (row 63 zeroed via guard) ----
            f32x16 accw;
            #pragma unroll
            for (int i = 0; i < 16; ++i) accw[i] = 0.f;
            {
                const bool ok = (32 + q5) < 63;
                const float* rp = rpw + (size_t)(32 + q5) * 64 + (g << 3);
                #pragma unroll
                for (int c = 0; c < 4; ++c) {
                    union { unsigned u[4]; bf16x8 v; } u;
                    if (ok) {
                        const f4 v0 = *(const f4*)(rp + (c << 4));
                        const f4 v1 = *(const f4*)(rp + (c << 4) + 4);
                        u.u[0] = pk2bf(v0.x, v0.y); u.u[1] = pk2bf(v0.z, v0.w);
                        u.u[2] = pk2bf(v1.x, v1.y); u.u[3] = pk2bf(v1.z, v1.w);
                    } else {
                        u.u[0] = 0u; u.u[1] = 0u; u.u[2] = 0u; u.u[3] = 0u;
                    }
                    accw = __builtin_amdgcn_mfma_f32_32x32x16_bf16(u.v, qf[c], accw, 0, 0, 0);
                }
            }
            #pragma unroll
            for (int r = 0; r < 16; ++r) {
                const int row = (r & 3) + ((r >> 2) << 3) + (g << 2) + 32;
                PwF[row * 33 + q5] = accw[r];
            }
        }
    }
    __syncthreads();

    // hoist rw from the Pw scratch: rel_w[srow][c*16+lr] = Pw[p][(s&31)+31-(c*16+lr)][s&31]
    float rw_[4][2];
    {
        const int p = w >> 1;
        const float* PwF = (float*)&KV[0][0] + p * 2112;
        #pragma unroll
        for (int reg = 0; reg < 4; ++reg) {
            const int q5w = ((w & 1) << 4) + (lg << 2) + reg;
            rw_[reg][0] = PwF[(q5w + 31 - lr) * 33 + q5w];
            rw_[reg][1] = PwF[(q5w + 15 - lr) * 33 + q5w];
        }
    }
    __syncthreads();   // Pw scratch dead; KV staging may begin

    // ======== main loop (R11 structure, rh from LDS) ========
    const ushort* qp = qbf + (((size_t)bn << 10) + q0 + w * 16 + lr) * DH + lg * 8;
    const bf16x8 qa0 = *(const bf16x8*)qp;
    const bf16x8 qa1 = *(const bf16x8*)(qp + 32);

    const int rhbase = ((w * 16 + lg * 4) << 1);

    const int i0   = w << 1;
    const int rsub = l >> 3;
    const int coff = ((l & 7) ^ rsub) << 3;
    const size_t kbase = ((size_t)bn << 16);
    const ushort* kp0 = kbf + kbase + (size_t)((i0 << 3) + rsub) * 64 + coff;
    const ushort* kp1 = kp0 + 512;
    const ushort* vp0 = vbfT + kbase + ((size_t)((i0 << 3) + rsub) << 10) + coff;
    const ushort* vp1 = vp0 + 8192;
    const int lds0 = i0 << 9;

    f32x4 oc[4];
    #pragma unroll
    for (int nf = 0; nf < 4; ++nf) oc[nf] = (f32x4){0.f, 0.f, 0.f, 0.f};
    f32x4 sumc = (f32x4){0.f, 0.f, 0.f, 0.f};
    bf16x8 ones;
    #pragma unroll
    for (int i = 0; i < 8; ++i) ones[i] = (short)0x3F80;   // bf16 1.0

    const int s0c = lg ^ (lr & 7);   // swizzled 16B-chunk index for reads

    // prologue: stage tile 0 into buf 0
    gload_lds16(kp0, &KV[0][lds0]);
    gload_lds16(kp1, &KV[0][lds0 + 512]);
    gload_lds16(vp0, &KV[0][4096 + lds0]);
    gload_lds16(vp1, &KV[0][4096 + lds0 + 512]);
    __syncthreads();

    for (int kt = 0; kt < 16; ++kt) {
        const int cur = kt & 1;
        if (kt < 15) {
            ushort* nb_ = &KV[cur ^ 1][0];
            gload_lds16(kp0 + ((kt + 1) << 12), nb_ + lds0);
            gload_lds16(kp1 + ((kt + 1) << 12), nb_ + lds0 + 512);
            gload_lds16(vp0 + ((kt + 1) << 6), nb_ + 4096 + lds0);
            gload_lds16(vp1 + ((kt + 1) << 6), nb_ + 4096 + lds0 + 512);
        }
        const ushort* Kl = &KV[cur][0];
        const ushort* Vt = &KV[cur][4096];
        const f4 rh01 = *(const f4*)&rhs_[(kt << 7) + rhbase];
        const f4 rh23 = *(const f4*)&rhs_[(kt << 7) + rhbase + 4];

        // ---- QK^T: S[16q x 64key] per wave ----
        f32x4 sc[4];
        #pragma unroll
        for (int f = 0; f < 4; ++f) {
            f32x4 c = (f32x4){0.f, 0.f, 0.f, 0.f};
            const int rb = (f * 16 + lr) * 64;
            const bf16x8 kb0 = *(const bf16x8*)&Kl[rb + (s0c << 3)];
            const bf16x8 kb1 = *(const bf16x8*)&Kl[rb + ((s0c ^ 4) << 3)];
            c = __builtin_amdgcn_mfma_f32_16x16x32_bf16(qa0, kb0, c, 0, 0, 0);
            c = __builtin_amdgcn_mfma_f32_16x16x32_bf16(qa1, kb1, c, 0, 0, 0);
            sc[f] = c;
        }

        // ---- bias + exp (no max shift), pack P (key' = lr*4+f) ----
        #pragma unroll
        for (int reg = 0; reg < 4; ++reg) {
            const float rhx = (reg == 0) ? rh01.x : (reg == 1) ? rh01.z
                             : (reg == 2) ? rh23.x : rh23.z;
            const float rhy = (reg == 0) ? rh01.y : (reg == 1) ? rh01.w
                             : (reg == 2) ? rh23.y : rh23.w;
            const float e0 = __expf(fmaf(sc[0][reg], 0.125f, rhx + rw_[reg][0]));
            const float e1 = __expf(fmaf(sc[1][reg], 0.125f, rhx + rw_[reg][1]));
            const float e2 = __expf(fmaf(sc[2][reg], 0.125f, rhy + rw_[reg][0]));
            const float e3 = __expf(fmaf(sc[3][reg], 0.125f, rhy + rw_[reg][1]));
            uint2 pk;
            pk.x = pk2bf(e0, e1);
            pk.y = pk2bf(e2, e3);
            *(uint2*)&Pl[w][lg * 4 + reg][lr * 4] = pk;
        }

        // ---- P frags, row-sum MFMA, PV ----
        const bf16x8 pa0 = *(const bf16x8*)&Pl[w][lr][lg * 8];
        const bf16x8 pa1 = *(const bf16x8*)&Pl[w][lr][lg * 8 + 32];
        sumc = __builtin_amdgcn_mfma_f32_16x16x32_bf16(pa0, ones, sumc, 0, 0, 0);
        sumc = __builtin_amdgcn_mfma_f32_16x16x32_bf16(pa1, ones, sumc, 0, 0, 0);
        #pragma unroll
        for (int nf = 0; nf < 4; ++nf) {
            const int rb = (nf * 16 + lr) * 64;
            const bf16x8 vb0 = *(const bf16x8*)&Vt[rb + (s0c << 3)];
            const bf16x8 vb1 = *(const bf16x8*)&Vt[rb + ((s0c ^ 4) << 3)];
            oc[nf] = __builtin_amdgcn_mfma_f32_16x16x32_bf16(pa0, vb0, oc[nf], 0, 0, 0);
            oc[nf] = __builtin_amdgcn_mfma_f32_16x16x32_bf16(pa1, vb1, oc[nf], 0, 0, 0);
        }
        __syncthreads();
    }

    // ---- normalize, write abf2[head][4096][64] -------------------------------
    const int bi = bn / NHD, hn = bn - bi * NHD;
    #pragma unroll
    for (int reg = 0; reg < 4; ++reg) {
        const float inv = 1.f / sumc[reg];
        const int row = q0 + w * 16 + lg * 4 + reg;
        ushort* dst = abf2 + ((size_t)hn * 4096 + (bi << 10) + row) * 64 + lr;
        union { unsigned u; ushort2 s2; } a, b;
        a.u = pk2bf(oc[0][reg] * inv, oc[1][reg] * inv);
        b.u = pk2bf(oc[2][reg] * inv, oc[3][reg] * inv);
        dst[0]  = a.s2.x;
        dst[16] = a.s2.y;
        dst[32] = b.s2.x;
        dst[48] = b.s2.y;
    }
}

// ---------------- output projection: bf16 MFMA GEMM, 2-phase dbuf -------------
// A = abf2 [panel p][4096][64]; B = pwbf2 [panel][768][64]; BK=64.
__global__ __launch_bounds__(256, 2) void proj_mfma(
    const ushort* __restrict__ abf2, const ushort* __restrict__ pwbf2,
    const float* __restrict__ pb, float* __restrict__ out)
{
    __shared__ __align__(16) ushort Sp[32768];   // buf b: A at b*16384, B at +8192

    const int t = threadIdx.x;
    const int w = t >> 6, l = t & 63;
    const int lr = l & 15, lg = l >> 4;
    const int n0 = blockIdx.x << 7;
    const int m0 = blockIdx.y << 7;

    const int srow = (w << 3) + (l >> 3);
    const int scol = (l & 7) << 3;
    const ushort* Agl = abf2 + (size_t)(m0 + srow) * 64 + scol;   // + p*4096*64
    const ushort* Bgl = pwbf2 + (size_t)(n0 + srow) * 64 + scol;  // + p*768*64

    f32x4 acc[4][4];
    #pragma unroll
    for (int mi = 0; mi < 4; ++mi)
        #pragma unroll
        for (int ni = 0; ni < 4; ++ni) acc[mi][ni] = (f32x4){0.f, 0.f, 0.f, 0.f};

    const int mb = (w >> 1) << 6, nb = (w & 1) << 6;

    #pragma unroll
    for (int i = 0; i < 4; ++i) {
        gload_lds16(Agl + (size_t)(i << 5) * 64, &Sp[(i << 11) + (w << 9)]);
        gload_lds16(Bgl + (size_t)(i << 5) * 64, &Sp[8192 + (i << 11) + (w << 9)]);
    }
    __syncthreads();

    for (int kt = 0; kt < 12; ++kt) {
        const int cb = (kt & 1) << 14;
        if (kt < 11) {
            const int nbuf = ((kt + 1) & 1) << 14;
            #pragma unroll
            for (int i = 0; i < 4; ++i) {
                gload_lds16(Agl + ((size_t)(kt + 1) * 4096 + (i << 5)) * 64,
                            &Sp[nbuf + (i << 11) + (w << 9)]);
                gload_lds16(Bgl + ((size_t)(kt + 1) * CD + (i << 5)) * 64,
                            &Sp[nbuf + 8192 + (i << 11) + (w << 9)]);
            }
        }
        #pragma unroll
        for (int kk = 0; kk < 2; ++kk) {
            bf16x8 af[4], bf[4];
            #pragma unroll
            for (int mi = 0; mi < 4; ++mi)
                af[mi] = *(const bf16x8*)&Sp[cb + (mb + (mi << 4) + lr) * 64 + (kk << 5) + (lg << 3)];
            #pragma unroll
            for (int ni = 0; ni < 4; ++ni)
                bf[ni] = *(const bf16x8*)&Sp[cb + 8192 + (nb + (ni << 4) + lr) * 64 + (kk << 5) + (lg << 3)];
            #pragma unroll
            for (int mi = 0; mi < 4; ++mi)
                #pragma unroll
                for (int ni = 0; ni < 4; ++ni)
                    acc[mi][ni] = __builtin_amdgcn_mfma_f32_16x16x32_bf16(af[mi], bf[ni], acc[mi][ni], 0, 0, 0);
        }
        __syncthreads();
    }

    float bl[4];
    #pragma unroll
    for (int ni = 0; ni < 4; ++ni) bl[ni] = pb[n0 + nb + (ni << 4) + lr];
    #pragma unroll
    for (int mi = 0; mi < 4; ++mi)
        #pragma unroll
        for (int ni = 0; ni < 4; ++ni)
            #pragma unroll
            for (int reg = 0; reg < 4; ++reg)
                out[(size_t)(m0 + mb + (mi << 4) + (lg << 2) + reg) * CD
                    + n0 + nb + (ni << 4) + lr] = acc[mi][ni][reg] + bl[ni];
}

extern "C" void kernel_launch(void* const* d_in, const int* in_sizes, int n_in,
                              void* d_out, int out_size, void* d_ws, size_t ws_size,
                              hipStream_t stream) {
    (void)in_sizes; (void)n_in; (void)out_size; (void)ws_size;
    const float* x   = (const float*)d_in[0];
    const float* Wq  = (const float*)d_in[1];
    const float* Wk  = (const float*)d_in[2];
    const float* Wv  = (const float*)d_in[3];
    const float* bq  = (const float*)d_in[4];
    const float* bk  = (const float*)d_in[5];
    const float* bv  = (const float*)d_in[6];
    const float* rph = (const float*)d_in[7];
    const float* rpw = (const float*)d_in[8];
    const float* pw  = (const float*)d_in[9];
    const float* pb  = (const float*)d_in[10];
    float* out = (float*)d_out;

    ushort* cvt  = (ushort*)d_ws;
    ushort* xbf  = cvt;
    ushort* wqbf = cvt + 3145728;
    ushort* wkbf = wqbf + 589824;
    ushort* wvbf = wkbf + 589824;
    ushort* pwbf = wvbf + 589824;      // panel layout [k/64][768][64]
    ushort* qbf  = pwbf + 589824;
    ushort* kbf  = qbf  + 3145728;
    ushort* vbfT = kbf  + 3145728;
    ushort* abf2 = vbfT + 3145728;     // [head][4096][64]

    hipLaunchKernelGGL(cvt_bf16_k, dim3(5376), dim3(256), 0, stream,
                       x, Wq, Wk, Wv, pw, cvt);
    hipLaunchKernelGGL(qkv_mfma, dim3(18, 32), dim3(256), 0, stream,
                       xbf, wqbf, wkbf, wvbf, bq, bk, bv, qbf, kbf, vbfT);
    hipLaunchKernelGGL(attn_mfma, dim3(16, 48), dim3(256), 0, stream,
                       qbf, kbf, vbfT, rph, rpw, abf2);
    hipLaunchKernelGGL(proj_mfma, dim3(6, 32), dim3(256), 0, stream,
                       abf2, pwbf, pb, out);
}

// Round 13
// 81.331 us; speedup vs baseline: 1.3976x; 1.0922x over previous
//
#include <hip/hip_runtime.h>
#include <hip/hip_bf16.h>
#include <math.h>

typedef float4 f4;
typedef __attribute__((ext_vector_type(8))) short bf16x8;
typedef __attribute__((ext_vector_type(4))) float f32x4;
typedef __attribute__((ext_vector_type(16))) float f32x16;

#define CD   768
#define SEQ  1024
#define NHD  12
#define DH   64

__device__ __forceinline__ ushort f2bf(float x) {
    union { __hip_bfloat16 h; ushort u; } v;
    v.h = __float2bfloat16(x);
    return v.u;
}
__device__ __forceinline__ unsigned pk2bf(float a, float b) {
    union { __hip_bfloat162 h; unsigned u; } v;
    v.h = __float22bfloat162_rn(make_float2(a, b));
    return v.u;
}
__device__ __forceinline__ void gload_lds16(const ushort* g, ushort* l) {
    __builtin_amdgcn_global_load_lds((const __attribute__((address_space(1))) void*)g,
                                     (__attribute__((address_space(3))) void*)l, 16, 0, 0);
}

// ---------------- fp32 -> bf16 conversion pre-pass ---------------------------
// x, Wq, Wk, Wv -> row-major bf16; pw -> panel layout [k/64][n][k%64]
__global__ __launch_bounds__(256) void cvt_bf16_k(
    const float* __restrict__ x, const float* __restrict__ Wq,
    const float* __restrict__ Wk, const float* __restrict__ Wv,
    const float* __restrict__ pw, ushort* __restrict__ dst)
{
    const int idx = blockIdx.x * 256 + threadIdx.x;
    if (idx >= 1376256) return;
    const int e = idx << 2;
    if (e < 4915200) {
        const float* src; int off;
        if      (e < 3145728) { src = x;  off = e; }
        else if (e < 3735552) { src = Wq; off = e - 3145728; }
        else if (e < 4325376) { src = Wk; off = e - 3735552; }
        else                  { src = Wv; off = e - 4325376; }
        const f4 v = *(const f4*)(src + off);
        uint2 o;
        o.x = pk2bf(v.x, v.y);
        o.y = pk2bf(v.z, v.w);
        *(uint2*)(dst + e) = o;
    } else {
        const int off = e - 4915200;          // pw linear = n*768 + k
        const int n = off / CD, k = off - n * CD;
        const f4 v = *(const f4*)(pw + off);
        uint2 o;
        o.x = pk2bf(v.x, v.y);
        o.y = pk2bf(v.z, v.w);
        *(uint2*)(dst + 4915200 + ((size_t)(k >> 6) * CD + n) * 64 + (k & 63)) = o;
    }
}

// ---------------- QKV projection: bf16 MFMA GEMM, 128x96 tile, 2-phase dbuf ---
// grid 24x32 = 768 blocks -> exactly 3 blocks per CU (perfect balance).
__global__ __launch_bounds__(256, 2) void qkv_mfma(
    const ushort* __restrict__ xbf,
    const ushort* __restrict__ wq, const ushort* __restrict__ wk, const ushort* __restrict__ wv,
    const float* __restrict__ bq, const float* __restrict__ bk, const float* __restrict__ bv,
    ushort* __restrict__ qbf, ushort* __restrict__ kbf, ushort* __restrict__ vbfT)
{
    // buf b (b*14336): A[128][64] at +0 (8192), B[96][64] at +8192 (6144)
    __shared__ __align__(16) ushort Sq[28672];

    const int t = threadIdx.x;
    const int w = t >> 6, l = t & 63;
    const int lr = l & 15, lg = l >> 4;
    const int n0 = blockIdx.x * 96;           // 0..2208
    const int m0 = blockIdx.y << 7;
    const int sel  = n0 / CD;
    const int nloc = n0 % CD;
    const ushort* Wb  = (sel == 0) ? wq : ((sel == 1) ? wk : wv);
    const float* bias = (sel == 0) ? bq : ((sel == 1) ? bk : bv);

    const int srow = (w << 3) + (l >> 3);
    const int scol = (l & 7) << 3;
    const ushort* Agl = xbf + (size_t)(m0 + srow) * CD + scol;
    const ushort* Bgl = Wb + (size_t)(nloc + srow) * CD + scol;

    f32x4 acc[4][3];
    #pragma unroll
    for (int mi = 0; mi < 4; ++mi)
        #pragma unroll
        for (int ni = 0; ni < 3; ++ni) acc[mi][ni] = (f32x4){0.f, 0.f, 0.f, 0.f};

    const int mb = (w >> 1) << 6;       // 0 / 64
    const int nb = (w & 1) * 48;        // 0 / 48

    // prologue: stage K-step 0 into buf 0
    #pragma unroll
    for (int i = 0; i < 4; ++i)
        gload_lds16(Agl + (size_t)(i << 5) * CD, &Sq[(i << 11) + (w << 9)]);
    #pragma unroll
    for (int i = 0; i < 3; ++i)
        gload_lds16(Bgl + (size_t)(i << 5) * CD, &Sq[8192 + (i << 11) + (w << 9)]);
    __syncthreads();

    for (int kt = 0; kt < 12; ++kt) {
        const int cb = (kt & 1) * 14336;
        if (kt < 11) {
            const int nbuf = ((kt + 1) & 1) * 14336;
            const int kc = (kt + 1) << 6;
            #pragma unroll
            for (int i = 0; i < 4; ++i)
                gload_lds16(Agl + (size_t)(i << 5) * CD + kc, &Sq[nbuf + (i << 11) + (w << 9)]);
            #pragma unroll
            for (int i = 0; i < 3; ++i)
                gload_lds16(Bgl + (size_t)(i << 5) * CD + kc, &Sq[nbuf + 8192 + (i << 11) + (w << 9)]);
        }
        #pragma unroll
        for (int kk = 0; kk < 2; ++kk) {
            bf16x8 af[4], bf[3];
            #pragma unroll
            for (int mi = 0; mi < 4; ++mi)
                af[mi] = *(const bf16x8*)&Sq[cb + (mb + (mi << 4) + lr) * 64 + (kk << 5) + (lg << 3)];
            #pragma unroll
            for (int ni = 0; ni < 3; ++ni)
                bf[ni] = *(const bf16x8*)&Sq[cb + 8192 + (nb + (ni << 4) + lr) * 64 + (kk << 5) + (lg << 3)];
            #pragma unroll
            for (int mi = 0; mi < 4; ++mi)
                #pragma unroll
                for (int ni = 0; ni < 3; ++ni)
                    acc[mi][ni] = __builtin_amdgcn_mfma_f32_16x16x32_bf16(af[mi], bf[ni], acc[mi][ni], 0, 0, 0);
        }
        __syncthreads();
    }

    ushort* Ep = Sq + w * 3072;          // per-wave 64x48 (q/k) or 48x64 (v)

    float bl[3];
    #pragma unroll
    for (int ni = 0; ni < 3; ++ni) bl[ni] = bias[nloc + nb + (ni << 4) + lr];

    if (sel < 2) {
        // Ep[row(64)][col(48)]
        #pragma unroll
        for (int mi = 0; mi < 4; ++mi)
            #pragma unroll
            for (int ni = 0; ni < 3; ++ni)
                #pragma unroll
                for (int reg = 0; reg < 4; ++reg)
                    Ep[((mi << 4) + (lg << 2) + reg) * 48 + (ni << 4) + lr] =
                        f2bf(acc[mi][ni][reg] + bl[ni]);
    } else {
        // V: transpose + key-permute within 64-block: Ep[d'(48)][s'(64)],
        // s' = ((lg*4+reg)<<2) + mi (key-permute preserved)
        #pragma unroll
        for (int mi = 0; mi < 4; ++mi)
            #pragma unroll
            for (int ni = 0; ni < 3; ++ni)
                #pragma unroll
                for (int reg = 0; reg < 4; ++reg)
                    Ep[((ni << 4) + lr) * 64 + (lg << 4) + (reg << 2) + mi] =
                        f2bf(acc[mi][ni][reg] + bl[ni]);
    }
    __syncthreads();

    const int bi  = m0 >> 10;
    const int si0 = (m0 & 1023) + mb;
    if (sel < 2) {
        ushort* dbf = (sel == 0) ? qbf : kbf;
        // 64 rows x 6 chunks; chunk never crosses a head boundary (16-aligned)
        #pragma unroll
        for (int i = 0; i < 6; ++i) {
            const int c0   = i << 3;
            const int head = (nloc + nb + c0) >> 6;
            const int dd0  = (nloc + nb + c0) & 63;
            const int bn   = bi * NHD + head;
            *(bf16x8*)(dbf + (((size_t)bn << 10) + si0 + l) * 64 + dd0) =
                *(const bf16x8*)(Ep + l * 48 + c0);
        }
    } else {
        // 48 d-rows x 8 chunks = 384 b128 stores over 6 iterations
        #pragma unroll
        for (int i = 0; i < 6; ++i) {
            const int idx = (i << 6) + l;
            const int r   = idx >> 3, ch = idx & 7;
            const int head = (nloc + nb + r) >> 6;
            const int d    = (nloc + nb + r) & 63;
            const int bn   = bi * NHD + head;
            *(bf16x8*)(vbfT + (((size_t)(bn * DH + d)) << 10) + si0 + (ch << 3)) =
                *(const bf16x8*)(Ep + r * 64 + (ch << 3));
        }
    }
}

// ---------------- MFMA flash attention + fused rel-pos prologue ---------------
// (byte-identical to R12)
__global__ __launch_bounds__(256, 3) void attn_mfma(
    const ushort* __restrict__ qbf, const ushort* __restrict__ kbf,
    const ushort* __restrict__ vbfT,
    const float* __restrict__ rph, const float* __restrict__ rpw,
    ushort* __restrict__ abf2)
{
    __shared__ __align__(16) ushort KV[2][8192];  // [buf][ K:0..4095 | V:4096.. ]
    __shared__ __align__(16) ushort Pl[4][16][72];
    __shared__ __align__(16) float rhs_[2048];    // [ktp16][row64][2]

    const int t  = threadIdx.x;
    const int l  = t & 63, w = t >> 6;
    const int lr = l & 15, lg = l >> 4;
    const int qt = blockIdx.x, bn = blockIdx.y;
    const int q0 = qt << 6;

    // ======== rel prologue ========
    {
        const int p   = w >> 1;
        const int sub = w & 1;
        const int h   = (qt << 1) + p;
        const int q5  = l & 31, g = l >> 5;

        const ushort* qp = qbf + (((size_t)bn << 10) + (h << 5) + q5) * 64 + (g << 3);
        bf16x8 qf[4];
        #pragma unroll
        for (int c = 0; c < 4; ++c) qf[c] = *(const bf16x8*)(qp + (c << 4));

        float* PwF = (float*)&KV[0][0] + p * 2112;   // [64][33] scratch

        if (sub == 0) {
            f32x16 acch;
            #pragma unroll
            for (int i = 0; i < 16; ++i) acch[i] = 0.f;
            {
                const float* rp = rph + (size_t)(h + 31 - q5) * 64 + (g << 3);
                #pragma unroll
                for (int c = 0; c < 4; ++c) {
                    const f4 v0 = *(const f4*)(rp + (c << 4));
                    const f4 v1 = *(const f4*)(rp + (c << 4) + 4);
                    union { unsigned u[4]; bf16x8 v; } u;
                    u.u[0] = pk2bf(v0.x, v0.y); u.u[1] = pk2bf(v0.z, v0.w);
                    u.u[2] = pk2bf(v1.x, v1.y); u.u[3] = pk2bf(v1.z, v1.w);
                    acch = __builtin_amdgcn_mfma_f32_32x32x16_bf16(u.v, qf[c], acch, 0, 0, 0);
                }
            }
            #pragma unroll
            for (int r = 0; r < 16; r += 2) {
                const int k2 = (r & 3) + ((r >> 2) << 3) + (g << 2);
                *(float2*)&rhs_[((k2 >> 1) << 7) + (((p << 5) + q5) << 1)] =
                    make_float2(acch[r], acch[r + 1]);
            }
            f32x16 accw;
            #pragma unroll
            for (int i = 0; i < 16; ++i) accw[i] = 0.f;
            {
                const float* rp = rpw + (size_t)q5 * 64 + (g << 3);
                #pragma unroll
                for (int c = 0; c < 4; ++c) {
                    const f4 v0 = *(const f4*)(rp + (c << 4));
                    const f4 v1 = *(const f4*)(rp + (c << 4) + 4);
                    union { unsigned u[4]; bf16x8 v; } u;
                    u.u[0] = pk2bf(v0.x, v0.y); u.u[1] = pk2bf(v0.z, v0.w);
                    u.u[2] = pk2bf(v1.x, v1.y); u.u[3] = pk2bf(v1.z, v1.w);
                    accw = __builtin_amdgcn_mfma_f32_32x32x16_bf16(u.v, qf[c], accw, 0, 0, 0);
                }
            }
            #pragma unroll
            for (int r = 0; r < 16; ++r) {
                const int row = (r & 3) + ((r >> 2) << 3) + (g << 2);
                PwF[row * 33 + q5] = accw[r];
            }
        } else {
            f32x16 accw;
            #pragma unroll
            for (int i = 0; i < 16; ++i) accw[i] = 0.f;
            {
                const bool ok = (32 + q5) < 63;
                const float* rp = rpw + (size_t)(32 + q5) * 64 + (g << 3);
                #pragma unroll
                for (int c = 0; c < 4; ++c) {
                    union { unsigned u[4]; bf16x8 v; } u;
                    if (ok) {
                        const f4 v0 = *(const f4*)(rp + (c << 4));
                        const f4 v1 = *(const f4*)(rp + (c << 4) + 4);
                        u.u[0] = pk2bf(v0.x, v0.y); u.u[1] = pk2bf(v0.z, v0.w);
                        u.u[2] = pk2bf(v1.x, v1.y); u.u[3] = pk2bf(v1.z, v1.w);
                    } else {
                        u.u[0] = 0u; u.u[1] = 0u; u.u[2] = 0u; u.u[3] = 0u;
                    }
                    accw = __builtin_amdgcn_mfma_f32_32x32x16_bf16(u.v, qf[c], accw, 0, 0, 0);
                }
            }
            #pragma unroll
            for (int r = 0; r < 16; ++r) {
                const int row = (r & 3) + ((r >> 2) << 3) + (g << 2) + 32;
                PwF[row * 33 + q5] = accw[r];
            }
        }
    }
    __syncthreads();

    float rw_[4][2];
    {
        const int p = w >> 1;
        const float* PwF = (float*)&KV[0][0] + p * 2112;
        #pragma unroll
        for (int reg = 0; reg < 4; ++reg) {
            const int q5w = ((w & 1) << 4) + (lg << 2) + reg;
            rw_[reg][0] = PwF[(q5w + 31 - lr) * 33 + q5w];
            rw_[reg][1] = PwF[(q5w + 15 - lr) * 33 + q5w];
        }
    }
    __syncthreads();

    // ======== main loop ========
    const ushort* qp = qbf + (((size_t)bn << 10) + q0 + w * 16 + lr) * DH + lg * 8;
    const bf16x8 qa0 = *(const bf16x8*)qp;
    const bf16x8 qa1 = *(const bf16x8*)(qp + 32);

    const int rhbase = ((w * 16 + lg * 4) << 1);

    const int i0   = w << 1;
    const int rsub = l >> 3;
    const int coff = ((l & 7) ^ rsub) << 3;
    const size_t kbase = ((size_t)bn << 16);
    const ushort* kp0 = kbf + kbase + (size_t)((i0 << 3) + rsub) * 64 + coff;
    const ushort* kp1 = kp0 + 512;
    const ushort* vp0 = vbfT + kbase + ((size_t)((i0 << 3) + rsub) << 10) + coff;
    const ushort* vp1 = vp0 + 8192;
    const int lds0 = i0 << 9;

    f32x4 oc[4];
    #pragma unroll
    for (int nf = 0; nf < 4; ++nf) oc[nf] = (f32x4){0.f, 0.f, 0.f, 0.f};
    f32x4 sumc = (f32x4){0.f, 0.f, 0.f, 0.f};
    bf16x8 ones;
    #pragma unroll
    for (int i = 0; i < 8; ++i) ones[i] = (short)0x3F80;

    const int s0c = lg ^ (lr & 7);

    gload_lds16(kp0, &KV[0][lds0]);
    gload_lds16(kp1, &KV[0][lds0 + 512]);
    gload_lds16(vp0, &KV[0][4096 + lds0]);
    gload_lds16(vp1, &KV[0][4096 + lds0 + 512]);
    __syncthreads();

    for (int kt = 0; kt < 16; ++kt) {
        const int cur = kt & 1;
        if (kt < 15) {
            ushort* nb_ = &KV[cur ^ 1][0];
            gload_lds16(kp0 + ((kt + 1) << 12), nb_ + lds0);
            gload_lds16(kp1 + ((kt + 1) << 12), nb_ + lds0 + 512);
            gload_lds16(vp0 + ((kt + 1) << 6), nb_ + 4096 + lds0);
            gload_lds16(vp1 + ((kt + 1) << 6), nb_ + 4096 + lds0 + 512);
        }
        const ushort* Kl = &KV[cur][0];
        const ushort* Vt = &KV[cur][4096];
        const f4 rh01 = *(const f4*)&rhs_[(kt << 7) + rhbase];
        const f4 rh23 = *(const f4*)&rhs_[(kt << 7) + rhbase + 4];

        f32x4 sc[4];
        #pragma unroll
        for (int f = 0; f < 4; ++f) {
            f32x4 c = (f32x4){0.f, 0.f, 0.f, 0.f};
            const int rb = (f * 16 + lr) * 64;
            const bf16x8 kb0 = *(const bf16x8*)&Kl[rb + (s0c << 3)];
            const bf16x8 kb1 = *(const bf16x8*)&Kl[rb + ((s0c ^ 4) << 3)];
            c = __builtin_amdgcn_mfma_f32_16x16x32_bf16(qa0, kb0, c, 0, 0, 0);
            c = __builtin_amdgcn_mfma_f32_16x16x32_bf16(qa1, kb1, c, 0, 0, 0);
            sc[f] = c;
        }

        #pragma unroll
        for (int reg = 0; reg < 4; ++reg) {
            const float rhx = (reg == 0) ? rh01.x : (reg == 1) ? rh01.z
                             : (reg == 2) ? rh23.x : rh23.z;
            const float rhy = (reg == 0) ? rh01.y : (reg == 1) ? rh01.w
                             : (reg == 2) ? rh23.y : rh23.w;
            const float e0 = __expf(fmaf(sc[0][reg], 0.125f, rhx + rw_[reg][0]));
            const float e1 = __expf(fmaf(sc[1][reg], 0.125f, rhx + rw_[reg][1]));
            const float e2 = __expf(fmaf(sc[2][reg], 0.125f, rhy + rw_[reg][0]));
            const float e3 = __expf(fmaf(sc[3][reg], 0.125f, rhy + rw_[reg][1]));
            uint2 pk;
            pk.x = pk2bf(e0, e1);
            pk.y = pk2bf(e2, e3);
            *(uint2*)&Pl[w][lg * 4 + reg][lr * 4] = pk;
        }

        const bf16x8 pa0 = *(const bf16x8*)&Pl[w][lr][lg * 8];
        const bf16x8 pa1 = *(const bf16x8*)&Pl[w][lr][lg * 8 + 32];
        sumc = __builtin_amdgcn_mfma_f32_16x16x32_bf16(pa0, ones, sumc, 0, 0, 0);
        sumc = __builtin_amdgcn_mfma_f32_16x16x32_bf16(pa1, ones, sumc, 0, 0, 0);
        #pragma unroll
        for (int nf = 0; nf < 4; ++nf) {
            const int rb = (nf * 16 + lr) * 64;
            const bf16x8 vb0 = *(const bf16x8*)&Vt[rb + (s0c << 3)];
            const bf16x8 vb1 = *(const bf16x8*)&Vt[rb + ((s0c ^ 4) << 3)];
            oc[nf] = __builtin_amdgcn_mfma_f32_16x16x32_bf16(pa0, vb0, oc[nf], 0, 0, 0);
            oc[nf] = __builtin_amdgcn_mfma_f32_16x16x32_bf16(pa1, vb1, oc[nf], 0, 0, 0);
        }
        __syncthreads();
    }

    const int bi = bn / NHD, hn = bn - bi * NHD;
    #pragma unroll
    for (int reg = 0; reg < 4; ++reg) {
        const float inv = 1.f / sumc[reg];
        const int row = q0 + w * 16 + lg * 4 + reg;
        ushort* dst = abf2 + ((size_t)hn * 4096 + (bi << 10) + row) * 64 + lr;
        union { unsigned u; ushort2 s2; } a, b;
        a.u = pk2bf(oc[0][reg] * inv, oc[1][reg] * inv);
        b.u = pk2bf(oc[2][reg] * inv, oc[3][reg] * inv);
        dst[0]  = a.s2.x;
        dst[16] = a.s2.y;
        dst[32] = b.s2.x;
        dst[48] = b.s2.y;
    }
}

// ---------------- output projection: 128x96 tile, grid 8x32 = 256 blocks ------
__global__ __launch_bounds__(256, 2) void proj_mfma(
    const ushort* __restrict__ abf2, const ushort* __restrict__ pwbf2,
    const float* __restrict__ pb, float* __restrict__ out)
{
    __shared__ __align__(16) ushort Sp[28672];   // buf b*14336: A +0, B +8192

    const int t = threadIdx.x;
    const int w = t >> 6, l = t & 63;
    const int lr = l & 15, lg = l >> 4;
    const int n0 = blockIdx.x * 96;
    const int m0 = blockIdx.y << 7;

    const int srow = (w << 3) + (l >> 3);
    const int scol = (l & 7) << 3;
    const ushort* Agl = abf2 + (size_t)(m0 + srow) * 64 + scol;   // + p*4096*64
    const ushort* Bgl = pwbf2 + (size_t)(n0 + srow) * 64 + scol;  // + p*768*64

    f32x4 acc[4][3];
    #pragma unroll
    for (int mi = 0; mi < 4; ++mi)
        #pragma unroll
        for (int ni = 0; ni < 3; ++ni) acc[mi][ni] = (f32x4){0.f, 0.f, 0.f, 0.f};

    const int mb = (w >> 1) << 6;
    const int nb = (w & 1) * 48;

    #pragma unroll
    for (int i = 0; i < 4; ++i)
        gload_lds16(Agl + (size_t)(i << 5) * 64, &Sp[(i << 11) + (w << 9)]);
    #pragma unroll
    for (int i = 0; i < 3; ++i)
        gload_lds16(Bgl + (size_t)(i << 5) * 64, &Sp[8192 + (i << 11) + (w << 9)]);
    __syncthreads();

    for (int kt = 0; kt < 12; ++kt) {
        const int cb = (kt & 1) * 14336;
        if (kt < 11) {
            const int nbuf = ((kt + 1) & 1) * 14336;
            #pragma unroll
            for (int i = 0; i < 4; ++i)
                gload_lds16(Agl + ((size_t)(kt + 1) * 4096 + (i << 5)) * 64,
                            &Sp[nbuf + (i << 11) + (w << 9)]);
            #pragma unroll
            for (int i = 0; i < 3; ++i)
                gload_lds16(Bgl + ((size_t)(kt + 1) * CD + (i << 5)) * 64,
                            &Sp[nbuf + 8192 + (i << 11) + (w << 9)]);
        }
        #pragma unroll
        for (int kk = 0; kk < 2; ++kk) {
            bf16x8 af[4], bf[3];
            #pragma unroll
            for (int mi = 0; mi < 4; ++mi)
                af[mi] = *(const bf16x8*)&Sp[cb + (mb + (mi << 4) + lr) * 64 + (kk << 5) + (lg << 3)];
            #pragma unroll
            for (int ni = 0; ni < 3; ++ni)
                bf[ni] = *(const bf16x8*)&Sp[cb + 8192 + (nb + (ni << 4) + lr) * 64 + (kk << 5) + (lg << 3)];
            #pragma unroll
            for (int mi = 0; mi < 4; ++mi)
                #pragma unroll
                for (int ni = 0; ni < 3; ++ni)
                    acc[mi][ni] = __builtin_amdgcn_mfma_f32_16x16x32_bf16(af[mi], bf[ni], acc[mi][ni], 0, 0, 0);
        }
        __syncthreads();
    }

    float bl[3];
    #pragma unroll
    for (int ni = 0; ni < 3; ++ni) bl[ni] = pb[n0 + nb + (ni << 4) + lr];
    #pragma unroll
    for (int mi = 0; mi < 4; ++mi)
        #pragma unroll
        for (int ni = 0; ni < 3; ++ni)
            #pragma unroll
            for (int reg = 0; reg < 4; ++reg)
                out[(size_t)(m0 + mb + (mi << 4) + (lg << 2) + reg) * CD
                    + n0 + nb + (ni << 4) + lr] = acc[mi][ni][reg] + bl[ni];
}

extern "C" void kernel_launch(void* const* d_in, const int* in_sizes, int n_in,
                              void* d_out, int out_size, void* d_ws, size_t ws_size,
                              hipStream_t stream) {
    (void)in_sizes; (void)n_in; (void)out_size; (void)ws_size;
    const float* x   = (const float*)d_in[0];
    const float* Wq  = (const float*)d_in[1];
    const float* Wk  = (const float*)d_in[2];
    const float* Wv  = (const float*)d_in[3];
    const float* bq  = (const float*)d_in[4];
    const float* bk  = (const float*)d_in[5];
    const float* bv  = (const float*)d_in[6];
    const float* rph = (const float*)d_in[7];
    const float* rpw = (const float*)d_in[8];
    const float* pw  = (const float*)d_in[9];
    const float* pb  = (const float*)d_in[10];
    float* out = (float*)d_out;

    ushort* cvt  = (ushort*)d_ws;
    ushort* xbf  = cvt;
    ushort* wqbf = cvt + 3145728;
    ushort* wkbf = wqbf + 589824;
    ushort* wvbf = wkbf + 589824;
    ushort* pwbf = wvbf + 589824;      // panel layout [k/64][768][64]
    ushort* qbf  = pwbf + 589824;
    ushort* kbf  = qbf  + 3145728;
    ushort* vbfT = kbf  + 3145728;
    ushort* abf2 = vbfT + 3145728;     // [head][4096][64]

    hipLaunchKernelGGL(cvt_bf16_k, dim3(5376), dim3(256), 0, stream,
                       x, Wq, Wk, Wv, pw, cvt);
    hipLaunchKernelGGL(qkv_mfma, dim3(24, 32), dim3(256), 0, stream,
                       xbf, wqbf, wkbf, wvbf, bq, bk, bv, qbf, kbf, vbfT);
    hipLaunchKernelGGL(attn_mfma, dim3(16, 48), dim3(256), 0, stream,
                       qbf, kbf, vbfT, rph, rpw, abf2);
    hipLaunchKernelGGL(proj_mfma, dim3(8, 32), dim3(256), 0, stream,
                       abf2, pwbf, pb, out);
}

// Round 14
// 81.058 us; speedup vs baseline: 1.4023x; 1.0034x over previous
//
#include <hip/hip_runtime.h>
#include <hip/hip_bf16.h>
#include <math.h>

typedef float4 f4;
typedef __attribute__((ext_vector_type(8))) short bf16x8;
typedef __attribute__((ext_vector_type(4))) float f32x4;
typedef __attribute__((ext_vector_type(16))) float f32x16;

#define CD   768
#define SEQ  1024
#define NHD  12
#define DH   64

__device__ __forceinline__ ushort f2bf(float x) {
    union { __hip_bfloat16 h; ushort u; } v;
    v.h = __float2bfloat16(x);
    return v.u;
}
__device__ __forceinline__ unsigned pk2bf(float a, float b) {
    union { __hip_bfloat162 h; unsigned u; } v;
    v.h = __float22bfloat162_rn(make_float2(a, b));
    return v.u;
}
__device__ __forceinline__ void gload_lds16(const ushort* g, ushort* l) {
    __builtin_amdgcn_global_load_lds((const __attribute__((address_space(1))) void*)g,
                                     (__attribute__((address_space(3))) void*)l, 16, 0, 0);
}

// ---------------- fp32 -> bf16 conversion pre-pass ---------------------------
// x, Wq, Wk, Wv -> row-major bf16; pw -> panel layout [k/64][n][k%64]
__global__ __launch_bounds__(256) void cvt_bf16_k(
    const float* __restrict__ x, const float* __restrict__ Wq,
    const float* __restrict__ Wk, const float* __restrict__ Wv,
    const float* __restrict__ pw, ushort* __restrict__ dst)
{
    const int idx = blockIdx.x * 256 + threadIdx.x;
    if (idx >= 1376256) return;
    const int e = idx << 2;
    if (e < 4915200) {
        const float* src; int off;
        if      (e < 3145728) { src = x;  off = e; }
        else if (e < 3735552) { src = Wq; off = e - 3145728; }
        else if (e < 4325376) { src = Wk; off = e - 3735552; }
        else                  { src = Wv; off = e - 4325376; }
        const f4 v = *(const f4*)(src + off);
        uint2 o;
        o.x = pk2bf(v.x, v.y);
        o.y = pk2bf(v.z, v.w);
        *(uint2*)(dst + e) = o;
    } else {
        const int off = e - 4915200;          // pw linear = n*768 + k
        const int n = off / CD, k = off - n * CD;
        const f4 v = *(const f4*)(pw + off);
        uint2 o;
        o.x = pk2bf(v.x, v.y);
        o.y = pk2bf(v.z, v.w);
        *(uint2*)(dst + 4915200 + ((size_t)(k >> 6) * CD + n) * 64 + (k & 63)) = o;
    }
}

// ---------------- QKV projection: bf16 MFMA GEMM, 128x96 tile, 2-phase dbuf ---
// grid 24x32 = 768 blocks -> exactly 3 blocks per CU (perfect balance).
__global__ __launch_bounds__(256, 2) void qkv_mfma(
    const ushort* __restrict__ xbf,
    const ushort* __restrict__ wq, const ushort* __restrict__ wk, const ushort* __restrict__ wv,
    const float* __restrict__ bq, const float* __restrict__ bk, const float* __restrict__ bv,
    ushort* __restrict__ qbf, ushort* __restrict__ kbf, ushort* __restrict__ vbfT)
{
    // buf b (b*14336): A[128][64] at +0 (8192), B[96][64] at +8192 (6144)
    __shared__ __align__(16) ushort Sq[28672];

    const int t = threadIdx.x;
    const int w = t >> 6, l = t & 63;
    const int lr = l & 15, lg = l >> 4;
    const int n0 = blockIdx.x * 96;           // 0..2208
    const int m0 = blockIdx.y << 7;
    const int sel  = n0 / CD;
    const int nloc = n0 % CD;
    const ushort* Wb  = (sel == 0) ? wq : ((sel == 1) ? wk : wv);
    const float* bias = (sel == 0) ? bq : ((sel == 1) ? bk : bv);

    const int srow = (w << 3) + (l >> 3);
    const int scol = (l & 7) << 3;
    const ushort* Agl = xbf + (size_t)(m0 + srow) * CD + scol;
    const ushort* Bgl = Wb + (size_t)(nloc + srow) * CD + scol;

    f32x4 acc[4][3];
    #pragma unroll
    for (int mi = 0; mi < 4; ++mi)
        #pragma unroll
        for (int ni = 0; ni < 3; ++ni) acc[mi][ni] = (f32x4){0.f, 0.f, 0.f, 0.f};

    const int mb = (w >> 1) << 6;       // 0 / 64
    const int nb = (w & 1) * 48;        // 0 / 48

    // prologue: stage K-step 0 into buf 0
    #pragma unroll
    for (int i = 0; i < 4; ++i)
        gload_lds16(Agl + (size_t)(i << 5) * CD, &Sq[(i << 11) + (w << 9)]);
    #pragma unroll
    for (int i = 0; i < 3; ++i)
        gload_lds16(Bgl + (size_t)(i << 5) * CD, &Sq[8192 + (i << 11) + (w << 9)]);
    __syncthreads();

    for (int kt = 0; kt < 12; ++kt) {
        const int cb = (kt & 1) * 14336;
        if (kt < 11) {
            const int nbuf = ((kt + 1) & 1) * 14336;
            const int kc = (kt + 1) << 6;
            #pragma unroll
            for (int i = 0; i < 4; ++i)
                gload_lds16(Agl + (size_t)(i << 5) * CD + kc, &Sq[nbuf + (i << 11) + (w << 9)]);
            #pragma unroll
            for (int i = 0; i < 3; ++i)
                gload_lds16(Bgl + (size_t)(i << 5) * CD + kc, &Sq[nbuf + 8192 + (i << 11) + (w << 9)]);
        }
        #pragma unroll
        for (int kk = 0; kk < 2; ++kk) {
            bf16x8 af[4], bf[3];
            #pragma unroll
            for (int mi = 0; mi < 4; ++mi)
                af[mi] = *(const bf16x8*)&Sq[cb + (mb + (mi << 4) + lr) * 64 + (kk << 5) + (lg << 3)];
            #pragma unroll
            for (int ni = 0; ni < 3; ++ni)
                bf[ni] = *(const bf16x8*)&Sq[cb + 8192 + (nb + (ni << 4) + lr) * 64 + (kk << 5) + (lg << 3)];
            #pragma unroll
            for (int mi = 0; mi < 4; ++mi)
                #pragma unroll
                for (int ni = 0; ni < 3; ++ni)
                    acc[mi][ni] = __builtin_amdgcn_mfma_f32_16x16x32_bf16(af[mi], bf[ni], acc[mi][ni], 0, 0, 0);
        }
        __syncthreads();
    }

    ushort* Ep = Sq + w * 3072;          // per-wave 64x48 (q/k) or 48x64 (v)

    float bl[3];
    #pragma unroll
    for (int ni = 0; ni < 3; ++ni) bl[ni] = bias[nloc + nb + (ni << 4) + lr];

    if (sel < 2) {
        // Ep[row(64)][col(48)]
        #pragma unroll
        for (int mi = 0; mi < 4; ++mi)
            #pragma unroll
            for (int ni = 0; ni < 3; ++ni)
                #pragma unroll
                for (int reg = 0; reg < 4; ++reg)
                    Ep[((mi << 4) + (lg << 2) + reg) * 48 + (ni << 4) + lr] =
                        f2bf(acc[mi][ni][reg] + bl[ni]);
    } else {
        // V: transpose + key-permute within 64-block: Ep[d'(48)][s'(64)],
        // s' = ((lg*4+reg)<<2) + mi (key-permute preserved)
        #pragma unroll
        for (int mi = 0; mi < 4; ++mi)
            #pragma unroll
            for (int ni = 0; ni < 3; ++ni)
                #pragma unroll
                for (int reg = 0; reg < 4; ++reg)
                    Ep[((ni << 4) + lr) * 64 + (lg << 4) + (reg << 2) + mi] =
                        f2bf(acc[mi][ni][reg] + bl[ni]);
    }
    __syncthreads();

    const int bi  = m0 >> 10;
    const int si0 = (m0 & 1023) + mb;
    if (sel < 2) {
        ushort* dbf = (sel == 0) ? qbf : kbf;
        // 64 rows x 6 chunks; chunk never crosses a head boundary (16-aligned)
        #pragma unroll
        for (int i = 0; i < 6; ++i) {
            const int c0   = i << 3;
            const int head = (nloc + nb + c0) >> 6;
            const int dd0  = (nloc + nb + c0) & 63;
            const int bn   = bi * NHD + head;
            *(bf16x8*)(dbf + (((size_t)bn << 10) + si0 + l) * 64 + dd0) =
                *(const bf16x8*)(Ep + l * 48 + c0);
        }
    } else {
        // 48 d-rows x 8 chunks = 384 b128 stores over 6 iterations
        #pragma unroll
        for (int i = 0; i < 6; ++i) {
            const int idx = (i << 6) + l;
            const int r   = idx >> 3, ch = idx & 7;
            const int head = (nloc + nb + r) >> 6;
            const int d    = (nloc + nb + r) & 63;
            const int bn   = bi * NHD + head;
            *(bf16x8*)(vbfT + (((size_t)(bn * DH + d)) << 10) + si0 + (ch << 3)) =
                *(const bf16x8*)(Ep + r * 64 + (ch << 3));
        }
    }
}

// ---------------- MFMA flash attention + fused rel-pos prologue ---------------
// (byte-identical to R12/R13)
__global__ __launch_bounds__(256, 3) void attn_mfma(
    const ushort* __restrict__ qbf, const ushort* __restrict__ kbf,
    const ushort* __restrict__ vbfT,
    const float* __restrict__ rph, const float* __restrict__ rpw,
    ushort* __restrict__ abf2)
{
    __shared__ __align__(16) ushort KV[2][8192];  // [buf][ K:0..4095 | V:4096.. ]
    __shared__ __align__(16) ushort Pl[4][16][72];
    __shared__ __align__(16) float rhs_[2048];    // [ktp16][row64][2]

    const int t  = threadIdx.x;
    const int l  = t & 63, w = t >> 6;
    const int lr = l & 15, lg = l >> 4;
    const int qt = blockIdx.x, bn = blockIdx.y;
    const int q0 = qt << 6;

    // ======== rel prologue ========
    {
        const int p   = w >> 1;
        const int sub = w & 1;
        const int h   = (qt << 1) + p;
        const int q5  = l & 31, g = l >> 5;

        const ushort* qp = qbf + (((size_t)bn << 10) + (h << 5) + q5) * 64 + (g << 3);
        bf16x8 qf[4];
        #pragma unroll
        for (int c = 0; c < 4; ++c) qf[c] = *(const bf16x8*)(qp + (c << 4));

        float* PwF = (float*)&KV[0][0] + p * 2112;   // [64][33] scratch

        if (sub == 0) {
            f32x16 acch;
            #pragma unroll
            for (int i = 0; i < 16; ++i) acch[i] = 0.f;
            {
                const float* rp = rph + (size_t)(h + 31 - q5) * 64 + (g << 3);
                #pragma unroll
                for (int c = 0; c < 4; ++c) {
                    const f4 v0 = *(const f4*)(rp + (c << 4));
                    const f4 v1 = *(const f4*)(rp + (c << 4) + 4);
                    union { unsigned u[4]; bf16x8 v; } u;
                    u.u[0] = pk2bf(v0.x, v0.y); u.u[1] = pk2bf(v0.z, v0.w);
                    u.u[2] = pk2bf(v1.x, v1.y); u.u[3] = pk2bf(v1.z, v1.w);
                    acch = __builtin_amdgcn_mfma_f32_32x32x16_bf16(u.v, qf[c], acch, 0, 0, 0);
                }
            }
            #pragma unroll
            for (int r = 0; r < 16; r += 2) {
                const int k2 = (r & 3) + ((r >> 2) << 3) + (g << 2);
                *(float2*)&rhs_[((k2 >> 1) << 7) + (((p << 5) + q5) << 1)] =
                    make_float2(acch[r], acch[r + 1]);
            }
            f32x16 accw;
            #pragma unroll
            for (int i = 0; i < 16; ++i) accw[i] = 0.f;
            {
                const float* rp = rpw + (size_t)q5 * 64 + (g << 3);
                #pragma unroll
                for (int c = 0; c < 4; ++c) {
                    const f4 v0 = *(const f4*)(rp + (c << 4));
                    const f4 v1 = *(const f4*)(rp + (c << 4) + 4);
                    union { unsigned u[4]; bf16x8 v; } u;
                    u.u[0] = pk2bf(v0.x, v0.y); u.u[1] = pk2bf(v0.z, v0.w);
                    u.u[2] = pk2bf(v1.x, v1.y); u.u[3] = pk2bf(v1.z, v1.w);
                    accw = __builtin_amdgcn_mfma_f32_32x32x16_bf16(u.v, qf[c], accw, 0, 0, 0);
                }
            }
            #pragma unroll
            for (int r = 0; r < 16; ++r) {
                const int row = (r & 3) + ((r >> 2) << 3) + (g << 2);
                PwF[row * 33 + q5] = accw[r];
            }
        } else {
            f32x16 accw;
            #pragma unroll
            for (int i = 0; i < 16; ++i) accw[i] = 0.f;
            {
                const bool ok = (32 + q5) < 63;
                const float* rp = rpw + (size_t)(32 + q5) * 64 + (g << 3);
                #pragma unroll
                for (int c = 0; c < 4; ++c) {
                    union { unsigned u[4]; bf16x8 v; } u;
                    if (ok) {
                        const f4 v0 = *(const f4*)(rp + (c << 4));
                        const f4 v1 = *(const f4*)(rp + (c << 4) + 4);
                        u.u[0] = pk2bf(v0.x, v0.y); u.u[1] = pk2bf(v0.z, v0.w);
                        u.u[2] = pk2bf(v1.x, v1.y); u.u[3] = pk2bf(v1.z, v1.w);
                    } else {
                        u.u[0] = 0u; u.u[1] = 0u; u.u[2] = 0u; u.u[3] = 0u;
                    }
                    accw = __builtin_amdgcn_mfma_f32_32x32x16_bf16(u.v, qf[c], accw, 0, 0, 0);
                }
            }
            #pragma unroll
            for (int r = 0; r < 16; ++r) {
                const int row = (r & 3) + ((r >> 2) << 3) + (g << 2) + 32;
                PwF[row * 33 + q5] = accw[r];
            }
        }
    }
    __syncthreads();

    float rw_[4][2];
    {
        const int p = w >> 1;
        const float* PwF = (float*)&KV[0][0] + p * 2112;
        #pragma unroll
        for (int reg = 0; reg < 4; ++reg) {
            const int q5w = ((w & 1) << 4) + (lg << 2) + reg;
            rw_[reg][0] = PwF[(q5w + 31 - lr) * 33 + q5w];
            rw_[reg][1] = PwF[(q5w + 15 - lr) * 33 + q5w];
        }
    }
    __syncthreads();

    // ======== main loop ========
    const ushort* qp = qbf + (((size_t)bn << 10) + q0 + w * 16 + lr) * DH + lg * 8;
    const bf16x8 qa0 = *(const bf16x8*)qp;
    const bf16x8 qa1 = *(const bf16x8*)(qp + 32);

    const int rhbase = ((w * 16 + lg * 4) << 1);

    const int i0   = w << 1;
    const int rsub = l >> 3;
    const int coff = ((l & 7) ^ rsub) << 3;
    const size_t kbase = ((size_t)bn << 16);
    const ushort* kp0 = kbf + kbase + (size_t)((i0 << 3) + rsub) * 64 + coff;
    const ushort* kp1 = kp0 + 512;
    const ushort* vp0 = vbfT + kbase + ((size_t)((i0 << 3) + rsub) << 10) + coff;
    const ushort* vp1 = vp0 + 8192;
    const int lds0 = i0 << 9;

    f32x4 oc[4];
    #pragma unroll
    for (int nf = 0; nf < 4; ++nf) oc[nf] = (f32x4){0.f, 0.f, 0.f, 0.f};
    f32x4 sumc = (f32x4){0.f, 0.f, 0.f, 0.f};
    bf16x8 ones;
    #pragma unroll
    for (int i = 0; i < 8; ++i) ones[i] = (short)0x3F80;

    const int s0c = lg ^ (lr & 7);

    gload_lds16(kp0, &KV[0][lds0]);
    gload_lds16(kp1, &KV[0][lds0 + 512]);
    gload_lds16(vp0, &KV[0][4096 + lds0]);
    gload_lds16(vp1, &KV[0][4096 + lds0 + 512]);
    __syncthreads();

    for (int kt = 0; kt < 16; ++kt) {
        const int cur = kt & 1;
        if (kt < 15) {
            ushort* nb_ = &KV[cur ^ 1][0];
            gload_lds16(kp0 + ((kt + 1) << 12), nb_ + lds0);
            gload_lds16(kp1 + ((kt + 1) << 12), nb_ + lds0 + 512);
            gload_lds16(vp0 + ((kt + 1) << 6), nb_ + 4096 + lds0);
            gload_lds16(vp1 + ((kt + 1) << 6), nb_ + 4096 + lds0 + 512);
        }
        const ushort* Kl = &KV[cur][0];
        const ushort* Vt = &KV[cur][4096];
        const f4 rh01 = *(const f4*)&rhs_[(kt << 7) + rhbase];
        const f4 rh23 = *(const f4*)&rhs_[(kt << 7) + rhbase + 4];

        f32x4 sc[4];
        #pragma unroll
        for (int f = 0; f < 4; ++f) {
            f32x4 c = (f32x4){0.f, 0.f, 0.f, 0.f};
            const int rb = (f * 16 + lr) * 64;
            const bf16x8 kb0 = *(const bf16x8*)&Kl[rb + (s0c << 3)];
            const bf16x8 kb1 = *(const bf16x8*)&Kl[rb + ((s0c ^ 4) << 3)];
            c = __builtin_amdgcn_mfma_f32_16x16x32_bf16(qa0, kb0, c, 0, 0, 0);
            c = __builtin_amdgcn_mfma_f32_16x16x32_bf16(qa1, kb1, c, 0, 0, 0);
            sc[f] = c;
        }

        #pragma unroll
        for (int reg = 0; reg < 4; ++reg) {
            const float rhx = (reg == 0) ? rh01.x : (reg == 1) ? rh01.z
                             : (reg == 2) ? rh23.x : rh23.z;
            const float rhy = (reg == 0) ? rh01.y : (reg == 1) ? rh01.w
                             : (reg == 2) ? rh23.y : rh23.w;
            const float e0 = __expf(fmaf(sc[0][reg], 0.125f, rhx + rw_[reg][0]));
            const float e1 = __expf(fmaf(sc[1][reg], 0.125f, rhx + rw_[reg][1]));
            const float e2 = __expf(fmaf(sc[2][reg], 0.125f, rhy + rw_[reg][0]));
            const float e3 = __expf(fmaf(sc[3][reg], 0.125f, rhy + rw_[reg][1]));
            uint2 pk;
            pk.x = pk2bf(e0, e1);
            pk.y = pk2bf(e2, e3);
            *(uint2*)&Pl[w][lg * 4 + reg][lr * 4] = pk;
        }

        const bf16x8 pa0 = *(const bf16x8*)&Pl[w][lr][lg * 8];
        const bf16x8 pa1 = *(const bf16x8*)&Pl[w][lr][lg * 8 + 32];
        sumc = __builtin_amdgcn_mfma_f32_16x16x32_bf16(pa0, ones, sumc, 0, 0, 0);
        sumc = __builtin_amdgcn_mfma_f32_16x16x32_bf16(pa1, ones, sumc, 0, 0, 0);
        #pragma unroll
        for (int nf = 0; nf < 4; ++nf) {
            const int rb = (nf * 16 + lr) * 64;
            const bf16x8 vb0 = *(const bf16x8*)&Vt[rb + (s0c << 3)];
            const bf16x8 vb1 = *(const bf16x8*)&Vt[rb + ((s0c ^ 4) << 3)];
            oc[nf] = __builtin_amdgcn_mfma_f32_16x16x32_bf16(pa0, vb0, oc[nf], 0, 0, 0);
            oc[nf] = __builtin_amdgcn_mfma_f32_16x16x32_bf16(pa1, vb1, oc[nf], 0, 0, 0);
        }
        __syncthreads();
    }

    const int bi = bn / NHD, hn = bn - bi * NHD;
    #pragma unroll
    for (int reg = 0; reg < 4; ++reg) {
        const float inv = 1.f / sumc[reg];
        const int row = q0 + w * 16 + lg * 4 + reg;
        ushort* dst = abf2 + ((size_t)hn * 4096 + (bi << 10) + row) * 64 + lr;
        union { unsigned u; ushort2 s2; } a, b;
        a.u = pk2bf(oc[0][reg] * inv, oc[1][reg] * inv);
        b.u = pk2bf(oc[2][reg] * inv, oc[3][reg] * inv);
        dst[0]  = a.s2.x;
        dst[16] = a.s2.y;
        dst[32] = b.s2.x;
        dst[48] = b.s2.y;
    }
}

// ---------------- output projection: 64x96 tile, grid 8x64 = 512 blocks -------
// 2 blocks/CU (perfectly balanced) so co-resident blocks hide the per-K-step
// barrier drain (the m114 overlap mechanism that gives qkv its throughput).
__global__ __launch_bounds__(256, 2) void proj_mfma(
    const ushort* __restrict__ abf2, const ushort* __restrict__ pwbf2,
    const float* __restrict__ pb, float* __restrict__ out)
{
    // buf b (b*10240): A[64][64] at +0 (4096 ush), B[96][64] at +4096 (6144 ush)
    __shared__ __align__(16) ushort Sp[20480];

    const int t = threadIdx.x;
    const int w = t >> 6, l = t & 63;
    const int lr = l & 15, lg = l >> 4;
    const int n0 = blockIdx.x * 96;
    const int m0 = blockIdx.y << 6;      // 64-row tiles

    const int srow = l >> 3;             // 0..7
    const int scol = (l & 7) << 3;
    // A: wave w stages rows [w*16 .. w*16+15] (2 instrs); panel term added in loop
    const ushort* Agl = abf2 + (size_t)(m0 + (w << 4) + srow) * 64 + scol;
    // B: wave w stages rows [w*24 .. w*24+23] (3 instrs)
    const ushort* Bgl = pwbf2 + (size_t)(n0 + w * 24 + srow) * 64 + scol;

    f32x4 acc[2][3];
    #pragma unroll
    for (int mi = 0; mi < 2; ++mi)
        #pragma unroll
        for (int ni = 0; ni < 3; ++ni) acc[mi][ni] = (f32x4){0.f, 0.f, 0.f, 0.f};

    const int mb = (w >> 1) << 5;        // 0 / 32
    const int nb = (w & 1) * 48;         // 0 / 48

    // prologue: stage panel 0 into buf 0
    #pragma unroll
    for (int i = 0; i < 2; ++i)
        gload_lds16(Agl + (i << 9), &Sp[(w << 10) + (i << 9)]);
    #pragma unroll
    for (int j = 0; j < 3; ++j)
        gload_lds16(Bgl + (j << 9), &Sp[4096 + w * 1536 + (j << 9)]);
    __syncthreads();

    for (int kt = 0; kt < 12; ++kt) {
        const int cb = (kt & 1) * 10240;
        if (kt < 11) {
            const int nbuf = ((kt + 1) & 1) * 10240;
            const size_t pA = (size_t)(kt + 1) * 262144;   // panel stride A (4096*64)
            const size_t pB = (size_t)(kt + 1) * 49152;    // panel stride B (768*64)
            #pragma unroll
            for (int i = 0; i < 2; ++i)
                gload_lds16(Agl + pA + (i << 9), &Sp[nbuf + (w << 10) + (i << 9)]);
            #pragma unroll
            for (int j = 0; j < 3; ++j)
                gload_lds16(Bgl + pB + (j << 9), &Sp[nbuf + 4096 + w * 1536 + (j << 9)]);
        }
        #pragma unroll
        for (int kk = 0; kk < 2; ++kk) {
            bf16x8 af[2], bf[3];
            #pragma unroll
            for (int mi = 0; mi < 2; ++mi)
                af[mi] = *(const bf16x8*)&Sp[cb + (mb + (mi << 4) + lr) * 64 + (kk << 5) + (lg << 3)];
            #pragma unroll
            for (int ni = 0; ni < 3; ++ni)
                bf[ni] = *(const bf16x8*)&Sp[cb + 4096 + (nb + (ni << 4) + lr) * 64 + (kk << 5) + (lg << 3)];
            #pragma unroll
            for (int mi = 0; mi < 2; ++mi)
                #pragma unroll
                for (int ni = 0; ni < 3; ++ni)
                    acc[mi][ni] = __builtin_amdgcn_mfma_f32_16x16x32_bf16(af[mi], bf[ni], acc[mi][ni], 0, 0, 0);
        }
        __syncthreads();
    }

    float bl[3];
    #pragma unroll
    for (int ni = 0; ni < 3; ++ni) bl[ni] = pb[n0 + nb + (ni << 4) + lr];
    #pragma unroll
    for (int mi = 0; mi < 2; ++mi)
        #pragma unroll
        for (int ni = 0; ni < 3; ++ni)
            #pragma unroll
            for (int reg = 0; reg < 4; ++reg)
                out[(size_t)(m0 + mb + (mi << 4) + (lg << 2) + reg) * CD
                    + n0 + nb + (ni << 4) + lr] = acc[mi][ni][reg] + bl[ni];
}

extern "C" void kernel_launch(void* const* d_in, const int* in_sizes, int n_in,
                              void* d_out, int out_size, void* d_ws, size_t ws_size,
                              hipStream_t stream) {
    (void)in_sizes; (void)n_in; (void)out_size; (void)ws_size;
    const float* x   = (const float*)d_in[0];
    const float* Wq  = (const float*)d_in[1];
    const float* Wk  = (const float*)d_in[2];
    const float* Wv  = (const float*)d_in[3];
    const float* bq  = (const float*)d_in[4];
    const float* bk  = (const float*)d_in[5];
    const float* bv  = (const float*)d_in[6];
    const float* rph = (const float*)d_in[7];
    const float* rpw = (const float*)d_in[8];
    const float* pw  = (const float*)d_in[9];
    const float* pb  = (const float*)d_in[10];
    float* out = (float*)d_out;

    ushort* cvt  = (ushort*)d_ws;
    ushort* xbf  = cvt;
    ushort* wqbf = cvt + 3145728;
    ushort* wkbf = wqbf + 589824;
    ushort* wvbf = wkbf + 589824;
    ushort* pwbf = wvbf + 589824;      // panel layout [k/64][768][64]
    ushort* qbf  = pwbf + 589824;
    ushort* kbf  = qbf  + 3145728;
    ushort* vbfT = kbf  + 3145728;
    ushort* abf2 = vbfT + 3145728;     // [head][4096][64]

    hipLaunchKernelGGL(cvt_bf16_k, dim3(5376), dim3(256), 0, stream,
                       x, Wq, Wk, Wv, pw, cvt);
    hipLaunchKernelGGL(qkv_mfma, dim3(24, 32), dim3(256), 0, stream,
                       xbf, wqbf, wkbf, wvbf, bq, bk, bv, qbf, kbf, vbfT);
    hipLaunchKernelGGL(attn_mfma, dim3(16, 48), dim3(256), 0, stream,
                       qbf, kbf, vbfT, rph, rpw, abf2);
    hipLaunchKernelGGL(proj_mfma, dim3(8, 64), dim3(256), 0, stream,
                       abf2, pwbf, pb, out);
}

// Round 15
// 79.607 us; speedup vs baseline: 1.4278x; 1.0182x over previous
//
#include <hip/hip_runtime.h>
#include <hip/hip_bf16.h>
#include <math.h>

typedef float4 f4;
typedef __attribute__((ext_vector_type(8))) short bf16x8;
typedef __attribute__((ext_vector_type(4))) float f32x4;
typedef __attribute__((ext_vector_type(16))) float f32x16;

#define CD   768
#define SEQ  1024
#define NHD  12
#define DH   64

__device__ __forceinline__ ushort f2bf(float x) {
    union { __hip_bfloat16 h; ushort u; } v;
    v.h = __float2bfloat16(x);
    return v.u;
}
__device__ __forceinline__ unsigned pk2bf(float a, float b) {
    union { __hip_bfloat162 h; unsigned u; } v;
    v.h = __float22bfloat162_rn(make_float2(a, b));
    return v.u;
}
__device__ __forceinline__ bf16x8 mk_bf16x8(unsigned a, unsigned b, unsigned c, unsigned d) {
    union { unsigned u[4]; bf16x8 v; } r;
    r.u[0] = a; r.u[1] = b; r.u[2] = c; r.u[3] = d;
    return r.v;
}
__device__ __forceinline__ void gload_lds16(const ushort* g, ushort* l) {
    __builtin_amdgcn_global_load_lds((const __attribute__((address_space(1))) void*)g,
                                     (__attribute__((address_space(3))) void*)l, 16, 0, 0);
}

// ---------------- fp32 -> bf16 conversion pre-pass ---------------------------
// x, Wq, Wk, Wv -> row-major bf16; pw -> panel layout [k/64][n][k%64]
__global__ __launch_bounds__(256) void cvt_bf16_k(
    const float* __restrict__ x, const float* __restrict__ Wq,
    const float* __restrict__ Wk, const float* __restrict__ Wv,
    const float* __restrict__ pw, ushort* __restrict__ dst)
{
    const int idx = blockIdx.x * 256 + threadIdx.x;
    if (idx >= 1376256) return;
    const int e = idx << 2;
    if (e < 4915200) {
        const float* src; int off;
        if      (e < 3145728) { src = x;  off = e; }
        else if (e < 3735552) { src = Wq; off = e - 3145728; }
        else if (e < 4325376) { src = Wk; off = e - 3735552; }
        else                  { src = Wv; off = e - 4325376; }
        const f4 v = *(const f4*)(src + off);
        uint2 o;
        o.x = pk2bf(v.x, v.y);
        o.y = pk2bf(v.z, v.w);
        *(uint2*)(dst + e) = o;
    } else {
        const int off = e - 4915200;          // pw linear = n*768 + k
        const int n = off / CD, k = off - n * CD;
        const f4 v = *(const f4*)(pw + off);
        uint2 o;
        o.x = pk2bf(v.x, v.y);
        o.y = pk2bf(v.z, v.w);
        *(uint2*)(dst + 4915200 + ((size_t)(k >> 6) * CD + n) * 64 + (k & 63)) = o;
    }
}

// ---------------- QKV projection: bf16 MFMA GEMM, 128x96 tile, 2-phase dbuf ---
// grid 24x32 = 768 blocks -> exactly 3 blocks per CU.
// V epilogue stores keys permuted by pi: key [f1 f0|lg1 lg0|r1 r0] ->
// slot [f1|lg1 lg0|f0|r1 r0], matching attn's in-register P fragments.
__global__ __launch_bounds__(256, 2) void qkv_mfma(
    const ushort* __restrict__ xbf,
    const ushort* __restrict__ wq, const ushort* __restrict__ wk, const ushort* __restrict__ wv,
    const float* __restrict__ bq, const float* __restrict__ bk, const float* __restrict__ bv,
    ushort* __restrict__ qbf, ushort* __restrict__ kbf, ushort* __restrict__ vbfT)
{
    // buf b (b*14336): A[128][64] at +0 (8192), B[96][64] at +8192 (6144)
    __shared__ __align__(16) ushort Sq[28672];

    const int t = threadIdx.x;
    const int w = t >> 6, l = t & 63;
    const int lr = l & 15, lg = l >> 4;
    const int n0 = blockIdx.x * 96;           // 0..2208
    const int m0 = blockIdx.y << 7;
    const int sel  = n0 / CD;
    const int nloc = n0 % CD;
    const ushort* Wb  = (sel == 0) ? wq : ((sel == 1) ? wk : wv);
    const float* bias = (sel == 0) ? bq : ((sel == 1) ? bk : bv);

    const int srow = (w << 3) + (l >> 3);
    const int scol = (l & 7) << 3;
    const ushort* Agl = xbf + (size_t)(m0 + srow) * CD + scol;
    const ushort* Bgl = Wb + (size_t)(nloc + srow) * CD + scol;

    f32x4 acc[4][3];
    #pragma unroll
    for (int mi = 0; mi < 4; ++mi)
        #pragma unroll
        for (int ni = 0; ni < 3; ++ni) acc[mi][ni] = (f32x4){0.f, 0.f, 0.f, 0.f};

    const int mb = (w >> 1) << 6;       // 0 / 64
    const int nb = (w & 1) * 48;        // 0 / 48

    #pragma unroll
    for (int i = 0; i < 4; ++i)
        gload_lds16(Agl + (size_t)(i << 5) * CD, &Sq[(i << 11) + (w << 9)]);
    #pragma unroll
    for (int i = 0; i < 3; ++i)
        gload_lds16(Bgl + (size_t)(i << 5) * CD, &Sq[8192 + (i << 11) + (w << 9)]);
    __syncthreads();

    for (int kt = 0; kt < 12; ++kt) {
        const int cb = (kt & 1) * 14336;
        if (kt < 11) {
            const int nbuf = ((kt + 1) & 1) * 14336;
            const int kc = (kt + 1) << 6;
            #pragma unroll
            for (int i = 0; i < 4; ++i)
                gload_lds16(Agl + (size_t)(i << 5) * CD + kc, &Sq[nbuf + (i << 11) + (w << 9)]);
            #pragma unroll
            for (int i = 0; i < 3; ++i)
                gload_lds16(Bgl + (size_t)(i << 5) * CD + kc, &Sq[nbuf + 8192 + (i << 11) + (w << 9)]);
        }
        #pragma unroll
        for (int kk = 0; kk < 2; ++kk) {
            bf16x8 af[4], bf[3];
            #pragma unroll
            for (int mi = 0; mi < 4; ++mi)
                af[mi] = *(const bf16x8*)&Sq[cb + (mb + (mi << 4) + lr) * 64 + (kk << 5) + (lg << 3)];
            #pragma unroll
            for (int ni = 0; ni < 3; ++ni)
                bf[ni] = *(const bf16x8*)&Sq[cb + 8192 + (nb + (ni << 4) + lr) * 64 + (kk << 5) + (lg << 3)];
            #pragma unroll
            for (int mi = 0; mi < 4; ++mi)
                #pragma unroll
                for (int ni = 0; ni < 3; ++ni)
                    acc[mi][ni] = __builtin_amdgcn_mfma_f32_16x16x32_bf16(af[mi], bf[ni], acc[mi][ni], 0, 0, 0);
        }
        __syncthreads();
    }

    ushort* Ep = Sq + w * 3072;          // per-wave 64x48 (q/k) or 48x64 (v)

    float bl[3];
    #pragma unroll
    for (int ni = 0; ni < 3; ++ni) bl[ni] = bias[nloc + nb + (ni << 4) + lr];

    if (sel < 2) {
        #pragma unroll
        for (int mi = 0; mi < 4; ++mi)
            #pragma unroll
            for (int ni = 0; ni < 3; ++ni)
                #pragma unroll
                for (int reg = 0; reg < 4; ++reg)
                    Ep[((mi << 4) + (lg << 2) + reg) * 48 + (ni << 4) + lr] =
                        f2bf(acc[mi][ni][reg] + bl[ni]);
    } else {
        // V: transpose + pi-permute within 64-block:
        // key = mi*16 + lg*4 + reg -> slot = (mi>>1)*32 + lg*8 + (mi&1)*4 + reg
        #pragma unroll
        for (int mi = 0; mi < 4; ++mi)
            #pragma unroll
            for (int ni = 0; ni < 3; ++ni)
                #pragma unroll
                for (int reg = 0; reg < 4; ++reg)
                    Ep[((ni << 4) + lr) * 64 +
                       ((mi >> 1) << 5) + (lg << 3) + ((mi & 1) << 2) + reg] =
                        f2bf(acc[mi][ni][reg] + bl[ni]);
    }
    __syncthreads();

    const int bi  = m0 >> 10;
    const int si0 = (m0 & 1023) + mb;
    if (sel < 2) {
        ushort* dbf = (sel == 0) ? qbf : kbf;
        #pragma unroll
        for (int i = 0; i < 6; ++i) {
            const int c0   = i << 3;
            const int head = (nloc + nb + c0) >> 6;
            const int dd0  = (nloc + nb + c0) & 63;
            const int bn   = bi * NHD + head;
            *(bf16x8*)(dbf + (((size_t)bn << 10) + si0 + l) * 64 + dd0) =
                *(const bf16x8*)(Ep + l * 48 + c0);
        }
    } else {
        #pragma unroll
        for (int i = 0; i < 6; ++i) {
            const int idx = (i << 6) + l;
            const int r   = idx >> 3, ch = idx & 7;
            const int head = (nloc + nb + r) >> 6;
            const int d    = (nloc + nb + r) & 63;
            const int bn   = bi * NHD + head;
            *(bf16x8*)(vbfT + (((size_t)(bn * DH + d)) << 10) + si0 + (ch << 3)) =
                *(const bf16x8*)(Ep + r * 64 + (ch << 3));
        }
    }
}

// ---------------- MFMA flash attention + fused rel prologue -------------------
// Swapped QK^T: sc[f] = mfma(K-frag, Q-frag) puts q = w*16+lr in C columns;
// each lane owns one q-row's 16 keys -> P assembled IN REGISTERS (no P LDS).
// V stored pi-permuted so PV A-frags are the pk2bf concatenation directly.
__global__ __launch_bounds__(256, 3) void attn_mfma(
    const ushort* __restrict__ qbf, const ushort* __restrict__ kbf,
    const ushort* __restrict__ vbfT,
    const float* __restrict__ rph, const float* __restrict__ rpw,
    ushort* __restrict__ abf2)
{
    __shared__ __align__(16) ushort KV[2][8192];  // [buf][ K:0..4095 | V:4096.. ]
    __shared__ __align__(16) float rhs_[2048];    // [ktp16][row64][2]

    const int t  = threadIdx.x;
    const int l  = t & 63, w = t >> 6;
    const int lr = l & 15, lg = l >> 4;
    const int qt = blockIdx.x, bn = blockIdx.y;
    const int q0 = qt << 6;

    // ======== rel prologue (R12-verified) ========
    {
        const int p   = w >> 1;
        const int sub = w & 1;
        const int h   = (qt << 1) + p;
        const int q5  = l & 31, g = l >> 5;

        const ushort* qp = qbf + (((size_t)bn << 10) + (h << 5) + q5) * 64 + (g << 3);
        bf16x8 qf[4];
        #pragma unroll
        for (int c = 0; c < 4; ++c) qf[c] = *(const bf16x8*)(qp + (c << 4));

        float* PwF = (float*)&KV[0][0] + p * 2112;   // [64][33] scratch

        if (sub == 0) {
            f32x16 acch;
            #pragma unroll
            for (int i = 0; i < 16; ++i) acch[i] = 0.f;
            {
                const float* rp = rph + (size_t)(h + 31 - q5) * 64 + (g << 3);
                #pragma unroll
                for (int c = 0; c < 4; ++c) {
                    const f4 v0 = *(const f4*)(rp + (c << 4));
                    const f4 v1 = *(const f4*)(rp + (c << 4) + 4);
                    union { unsigned u[4]; bf16x8 v; } u;
                    u.u[0] = pk2bf(v0.x, v0.y); u.u[1] = pk2bf(v0.z, v0.w);
                    u.u[2] = pk2bf(v1.x, v1.y); u.u[3] = pk2bf(v1.z, v1.w);
                    acch = __builtin_amdgcn_mfma_f32_32x32x16_bf16(u.v, qf[c], acch, 0, 0, 0);
                }
            }
            #pragma unroll
            for (int r = 0; r < 16; r += 2) {
                const int k2 = (r & 3) + ((r >> 2) << 3) + (g << 2);
                *(float2*)&rhs_[((k2 >> 1) << 7) + (((p << 5) + q5) << 1)] =
                    make_float2(acch[r], acch[r + 1]);
            }
            f32x16 accw;
            #pragma unroll
            for (int i = 0; i < 16; ++i) accw[i] = 0.f;
            {
                const float* rp = rpw + (size_t)q5 * 64 + (g << 3);
                #pragma unroll
                for (int c = 0; c < 4; ++c) {
                    const f4 v0 = *(const f4*)(rp + (c << 4));
                    const f4 v1 = *(const f4*)(rp + (c << 4) + 4);
                    union { unsigned u[4]; bf16x8 v; } u;
                    u.u[0] = pk2bf(v0.x, v0.y); u.u[1] = pk2bf(v0.z, v0.w);
                    u.u[2] = pk2bf(v1.x, v1.y); u.u[3] = pk2bf(v1.z, v1.w);
                    accw = __builtin_amdgcn_mfma_f32_32x32x16_bf16(u.v, qf[c], accw, 0, 0, 0);
                }
            }
            #pragma unroll
            for (int r = 0; r < 16; ++r) {
                const int row = (r & 3) + ((r >> 2) << 3) + (g << 2);
                PwF[row * 33 + q5] = accw[r];
            }
        } else {
            f32x16 accw;
            #pragma unroll
            for (int i = 0; i < 16; ++i) accw[i] = 0.f;
            {
                const bool ok = (32 + q5) < 63;
                const float* rp = rpw + (size_t)(32 + q5) * 64 + (g << 3);
                #pragma unroll
                for (int c = 0; c < 4; ++c) {
                    union { unsigned u[4]; bf16x8 v; } u;
                    if (ok) {
                        const f4 v0 = *(const f4*)(rp + (c << 4));
                        const f4 v1 = *(const f4*)(rp + (c << 4) + 4);
                        u.u[0] = pk2bf(v0.x, v0.y); u.u[1] = pk2bf(v0.z, v0.w);
                        u.u[2] = pk2bf(v1.x, v1.y); u.u[3] = pk2bf(v1.z, v1.w);
                    } else {
                        u.u[0] = 0u; u.u[1] = 0u; u.u[2] = 0u; u.u[3] = 0u;
                    }
                    accw = __builtin_amdgcn_mfma_f32_32x32x16_bf16(u.v, qf[c], accw, 0, 0, 0);
                }
            }
            #pragma unroll
            for (int r = 0; r < 16; ++r) {
                const int row = (r & 3) + ((r >> 2) << 3) + (g << 2) + 32;
                PwF[row * 33 + q5] = accw[r];
            }
        }
    }
    __syncthreads();

    // hoist rel_w: lane's q = w*16 + lr; rw8[b*4+reg] = rel_w[q][b*16+lg*4+reg]
    float rw8[8];
    {
        const int p   = w >> 1;
        const int q5w = ((w & 1) << 4) + lr;     // q & 31
        const float* PwF = (float*)&KV[0][0] + p * 2112;
        #pragma unroll
        for (int b = 0; b < 2; ++b)
            #pragma unroll
            for (int reg = 0; reg < 4; ++reg) {
                const int k2 = (b << 4) + (lg << 2) + reg;
                rw8[(b << 2) + reg] = PwF[(q5w + 31 - k2) * 33 + q5w];
            }
    }
    __syncthreads();   // Pw scratch dead; KV staging may begin

    // ======== main loop ========
    const ushort* qp = qbf + (((size_t)bn << 10) + q0 + w * 16 + lr) * DH + lg * 8;
    const bf16x8 qa0 = *(const bf16x8*)qp;
    const bf16x8 qa1 = *(const bf16x8*)(qp + 32);

    const int rhbase = (w * 16 + lr) << 1;       // per-lane q row in rhs_

    const int i0   = w << 1;
    const int rsub = l >> 3;
    const int coff = ((l & 7) ^ rsub) << 3;
    const size_t kbase = ((size_t)bn << 16);
    const ushort* kp0 = kbf + kbase + (size_t)((i0 << 3) + rsub) * 64 + coff;
    const ushort* kp1 = kp0 + 512;
    const ushort* vp0 = vbfT + kbase + ((size_t)((i0 << 3) + rsub) << 10) + coff;
    const ushort* vp1 = vp0 + 8192;
    const int lds0 = i0 << 9;

    f32x4 oc[4];
    #pragma unroll
    for (int nf = 0; nf < 4; ++nf) oc[nf] = (f32x4){0.f, 0.f, 0.f, 0.f};
    f32x4 sumc = (f32x4){0.f, 0.f, 0.f, 0.f};
    bf16x8 ones;
    #pragma unroll
    for (int i = 0; i < 8; ++i) ones[i] = (short)0x3F80;

    const int s0c = lg ^ (lr & 7);

    gload_lds16(kp0, &KV[0][lds0]);
    gload_lds16(kp1, &KV[0][lds0 + 512]);
    gload_lds16(vp0, &KV[0][4096 + lds0]);
    gload_lds16(vp1, &KV[0][4096 + lds0 + 512]);
    __syncthreads();

    for (int kt = 0; kt < 16; ++kt) {
        const int cur = kt & 1;
        if (kt < 15) {
            ushort* nb_ = &KV[cur ^ 1][0];
            gload_lds16(kp0 + ((kt + 1) << 12), nb_ + lds0);
            gload_lds16(kp1 + ((kt + 1) << 12), nb_ + lds0 + 512);
            gload_lds16(vp0 + ((kt + 1) << 6), nb_ + 4096 + lds0);
            gload_lds16(vp1 + ((kt + 1) << 6), nb_ + 4096 + lds0 + 512);
        }
        const ushort* Kl = &KV[cur][0];
        const ushort* Vt = &KV[cur][4096];
        const float2 rh = *(const float2*)&rhs_[(kt << 7) + rhbase];

        // ---- swapped QK^T: sc[f][reg] = S[key=f*16+lg*4+reg][q=w*16+lr] ----
        f32x4 sc[4];
        #pragma unroll
        for (int f = 0; f < 4; ++f) {
            f32x4 c = (f32x4){0.f, 0.f, 0.f, 0.f};
            const int rb = (f * 16 + lr) * 64;
            const bf16x8 kb0 = *(const bf16x8*)&Kl[rb + (s0c << 3)];
            const bf16x8 kb1 = *(const bf16x8*)&Kl[rb + ((s0c ^ 4) << 3)];
            c = __builtin_amdgcn_mfma_f32_16x16x32_bf16(kb0, qa0, c, 0, 0, 0);
            c = __builtin_amdgcn_mfma_f32_16x16x32_bf16(kb1, qa1, c, 0, 0, 0);
            sc[f] = c;
        }

        // ---- bias + exp, assemble P A-frags in registers ----
        unsigned ua[4], ub[4];
        #pragma unroll
        for (int f = 0; f < 4; ++f) {
            const float rhv = (f & 2) ? rh.y : rh.x;
            const int rb8 = (f & 1) << 2;
            const float e0 = __expf(fmaf(sc[f][0], 0.125f, rhv + rw8[rb8 + 0]));
            const float e1 = __expf(fmaf(sc[f][1], 0.125f, rhv + rw8[rb8 + 1]));
            const float e2 = __expf(fmaf(sc[f][2], 0.125f, rhv + rw8[rb8 + 2]));
            const float e3 = __expf(fmaf(sc[f][3], 0.125f, rhv + rw8[rb8 + 3]));
            unsigned* du = (f & 2) ? ub : ua;
            du[((f & 1) << 1) + 0] = pk2bf(e0, e1);
            du[((f & 1) << 1) + 1] = pk2bf(e2, e3);
        }
        const bf16x8 pa0 = mk_bf16x8(ua[0], ua[1], ua[2], ua[3]);
        const bf16x8 pa1 = mk_bf16x8(ub[0], ub[1], ub[2], ub[3]);

        // ---- row-sum MFMA, PV ----
        sumc = __builtin_amdgcn_mfma_f32_16x16x32_bf16(pa0, ones, sumc, 0, 0, 0);
        sumc = __builtin_amdgcn_mfma_f32_16x16x32_bf16(pa1, ones, sumc, 0, 0, 0);
        #pragma unroll
        for (int nf = 0; nf < 4; ++nf) {
            const int rb = (nf * 16 + lr) * 64;
            const bf16x8 vb0 = *(const bf16x8*)&Vt[rb + (s0c << 3)];
            const bf16x8 vb1 = *(const bf16x8*)&Vt[rb + ((s0c ^ 4) << 3)];
            oc[nf] = __builtin_amdgcn_mfma_f32_16x16x32_bf16(pa0, vb0, oc[nf], 0, 0, 0);
            oc[nf] = __builtin_amdgcn_mfma_f32_16x16x32_bf16(pa1, vb1, oc[nf], 0, 0, 0);
        }
        __syncthreads();
    }

    // ---- normalize, write abf2[head][4096][64] -------------------------------
    const int bi = bn / NHD, hn = bn - bi * NHD;
    #pragma unroll
    for (int reg = 0; reg < 4; ++reg) {
        const float inv = 1.f / sumc[reg];
        const int row = q0 + w * 16 + lg * 4 + reg;
        ushort* dst = abf2 + ((size_t)hn * 4096 + (bi << 10) + row) * 64 + lr;
        union { unsigned u; ushort2 s2; } a, b;
        a.u = pk2bf(oc[0][reg] * inv, oc[1][reg] * inv);
        b.u = pk2bf(oc[2][reg] * inv, oc[3][reg] * inv);
        dst[0]  = a.s2.x;
        dst[16] = a.s2.y;
        dst[32] = b.s2.x;
        dst[48] = b.s2.y;
    }
}

// ---------------- output projection: 64x96 tile, grid 8x64 = 512 blocks -------
__global__ __launch_bounds__(256, 2) void proj_mfma(
    const ushort* __restrict__ abf2, const ushort* __restrict__ pwbf2,
    const float* __restrict__ pb, float* __restrict__ out)
{
    // buf b (b*10240): A[64][64] at +0 (4096 ush), B[96][64] at +4096 (6144 ush)
    __shared__ __align__(16) ushort Sp[20480];

    const int t = threadIdx.x;
    const int w = t >> 6, l = t & 63;
    const int lr = l & 15, lg = l >> 4;
    const int n0 = blockIdx.x * 96;
    const int m0 = blockIdx.y << 6;

    const int srow = l >> 3;
    const int scol = (l & 7) << 3;
    const ushort* Agl = abf2 + (size_t)(m0 + (w << 4) + srow) * 64 + scol;
    const ushort* Bgl = pwbf2 + (size_t)(n0 + w * 24 + srow) * 64 + scol;

    f32x4 acc[2][3];
    #pragma unroll
    for (int mi = 0; mi < 2; ++mi)
        #pragma unroll
        for (int ni = 0; ni < 3; ++ni) acc[mi][ni] = (f32x4){0.f, 0.f, 0.f, 0.f};

    const int mb = (w >> 1) << 5;
    const int nb = (w & 1) * 48;

    #pragma unroll
    for (int i = 0; i < 2; ++i)
        gload_lds16(Agl + (i << 9), &Sp[(w << 10) + (i << 9)]);
    #pragma unroll
    for (int j = 0; j < 3; ++j)
        gload_lds16(Bgl + (j << 9), &Sp[4096 + w * 1536 + (j << 9)]);
    __syncthreads();

    for (int kt = 0; kt < 12; ++kt) {
        const int cb = (kt & 1) * 10240;
        if (kt < 11) {
            const int nbuf = ((kt + 1) & 1) * 10240;
            const size_t pA = (size_t)(kt + 1) * 262144;
            const size_t pB = (size_t)(kt + 1) * 49152;
            #pragma unroll
            for (int i = 0; i < 2; ++i)
                gload_lds16(Agl + pA + (i << 9), &Sp[nbuf + (w << 10) + (i << 9)]);
            #pragma unroll
            for (int j = 0; j < 3; ++j)
                gload_lds16(Bgl + pB + (j << 9), &Sp[nbuf + 4096 + w * 1536 + (j << 9)]);
        }
        #pragma unroll
        for (int kk = 0; kk < 2; ++kk) {
            bf16x8 af[2], bf[3];
            #pragma unroll
            for (int mi = 0; mi < 2; ++mi)
                af[mi] = *(const bf16x8*)&Sp[cb + (mb + (mi << 4) + lr) * 64 + (kk << 5) + (lg << 3)];
            #pragma unroll
            for (int ni = 0; ni < 3; ++ni)
                bf[ni] = *(const bf16x8*)&Sp[cb + 4096 + (nb + (ni << 4) + lr) * 64 + (kk << 5) + (lg << 3)];
            #pragma unroll
            for (int mi = 0; mi < 2; ++mi)
                #pragma unroll
                for (int ni = 0; ni < 3; ++ni)
                    acc[mi][ni] = __builtin_amdgcn_mfma_f32_16x16x32_bf16(af[mi], bf[ni], acc[mi][ni], 0, 0, 0);
        }
        __syncthreads();
    }

    float bl[3];
    #pragma unroll
    for (int ni = 0; ni < 3; ++ni) bl[ni] = pb[n0 + nb + (ni << 4) + lr];
    #pragma unroll
    for (int mi = 0; mi < 2; ++mi)
        #pragma unroll
        for (int ni = 0; ni < 3; ++ni)
            #pragma unroll
            for (int reg = 0; reg < 4; ++reg)
                out[(size_t)(m0 + mb + (mi << 4) + (lg << 2) + reg) * CD
                    + n0 + nb + (ni << 4) + lr] = acc[mi][ni][reg] + bl[ni];
}

extern "C" void kernel_launch(void* const* d_in, const int* in_sizes, int n_in,
                              void* d_out, int out_size, void* d_ws, size_t ws_size,
                              hipStream_t stream) {
    (void)in_sizes; (void)n_in; (void)out_size; (void)ws_size;
    const float* x   = (const float*)d_in[0];
    const float* Wq  = (const float*)d_in[1];
    const float* Wk  = (const float*)d_in[2];
    const float* Wv  = (const float*)d_in[3];
    const float* bq  = (const float*)d_in[4];
    const float* bk  = (const float*)d_in[5];
    const float* bv  = (const float*)d_in[6];
    const float* rph = (const float*)d_in[7];
    const float* rpw = (const float*)d_in[8];
    const float* pw  = (const float*)d_in[9];
    const float* pb  = (const float*)d_in[10];
    float* out = (float*)d_out;

    ushort* cvt  = (ushort*)d_ws;
    ushort* xbf  = cvt;
    ushort* wqbf = cvt + 3145728;
    ushort* wkbf = wqbf + 589824;
    ushort* wvbf = wkbf + 589824;
    ushort* pwbf = wvbf + 589824;      // panel layout [k/64][768][64]
    ushort* qbf  = pwbf + 589824;
    ushort* kbf  = qbf  + 3145728;
    ushort* vbfT = kbf  + 3145728;
    ushort* abf2 = vbfT + 3145728;     // [head][4096][64]

    hipLaunchKernelGGL(cvt_bf16_k, dim3(5376), dim3(256), 0, stream,
                       x, Wq, Wk, Wv, pw, cvt);
    hipLaunchKernelGGL(qkv_mfma, dim3(24, 32), dim3(256), 0, stream,
                       xbf, wqbf, wkbf, wvbf, bq, bk, bv, qbf, kbf, vbfT);
    hipLaunchKernelGGL(attn_mfma, dim3(16, 48), dim3(256), 0, stream,
                       qbf, kbf, vbfT, rph, rpw, abf2);
    hipLaunchKernelGGL(proj_mfma, dim3(8, 64), dim3(256), 0, stream,
                       abf2, pwbf, pb, out);
}